// Round 5
// baseline (743.574 us; speedup 1.0000x reference)
//
#include <hip/hip_runtime.h>
#include <math.h>

#define D_DIM 3072
#define H_DIM 1024
#define Z_DIM 32
#define BATCH 128
#define NNEI 32
#define NROWS (BATCH * NNEI) /* 4096 */
#define MENC (NROWS + BATCH) /* 4224 */

typedef __attribute__((ext_vector_type(8))) short short8;
typedef __attribute__((ext_vector_type(4))) float f32x4;
typedef unsigned short ushortT;

__device__ __forceinline__ unsigned short f2bf(float f) {
  union { float f; unsigned int u; } v; v.f = f;
  unsigned int r = v.u + 0x7FFFu + ((v.u >> 16) & 1u);
  return (unsigned short)(r >> 16);
}
__device__ __forceinline__ float bf2f(unsigned short b) {
  union { unsigned int u; float f; } v; v.u = ((unsigned int)b) << 16;
  return v.f;
}

enum { EP_RELU = 0, EP_BIAS = 1, EP_LOSS = 2 };

// bf16 MFMA GEMM with REGISTER-PREFETCH staging (global->VGPR->ds_write).
// Key property vs global_load_lds: the vmcnt wait for tile k+1 happens at the
// ds_write AFTER all of tile k's ds_read+MFMA work, so global-load latency is
// hidden inside a single block (no reliance on occupancy; the barrier's
// vmcnt(0) drain is naturally satisfied by then).
// A: MxK bf16 row-major, BT: NxK bf16 (B transposed). Tile TM x TN, 4 waves
// in 2x2 (wave tile TM/2 x TN/2), mfma_f32_16x16x32_bf16, BK in {32,64}.
// LDS layout: set s (64 lanes x 16B = 1 KB) = [kk][chunk] fragment order;
// ds_read_b128/ds_write_b128 both conflict-free (lane*16B contiguous).
// Requires M%TM==0, N%TN==0, K%BK==0.
template <int MODE, int TM, int TN, int BK>
__global__ __launch_bounds__(256) void gemm_rp(
    const ushortT* __restrict__ A, const ushortT* __restrict__ BT,
    const float* __restrict__ bias, ushortT* __restrict__ C,
    int M, int N, int K,
    const ushortT* __restrict__ xa,    // EP_LOSS: M x N bf16 (x_nn)
    const float* __restrict__ wrow,    // EP_LOSS: per-row weight
    float* __restrict__ out) {
  constexpr int MF = TM / 32;              // m-frags per wave
  constexpr int NF = TN / 32;              // n-frags per wave
  constexpr int KI = BK / 32;              // k-steps per iter
  constexpr int CHA = TM / 16;             // A chunks per k-half
  constexpr int CHB = TN / 16;
  constexpr int SETS_A = CHA * KI;
  constexpr int SETS = (CHA + CHB) * KI;
  constexpr int SPW = SETS / 4;            // staging sets per wave

  __shared__ __align__(16) ushortT Ls[(TM + TN) * BK];
  __shared__ float red[256];

  const int t = threadIdx.x;
  const int wave = t >> 6;
  const int lane = t & 63;
  const int quad = lane >> 4;
  const int lm = lane & 15;
  const int bm = blockIdx.y * TM;
  const int bn = blockIdx.x * TN;
  const int wr = (wave >> 1) * (TM / 2);
  const int wc = (wave & 1) * (TN / 2);

  f32x4 acc[MF][NF];
#pragma unroll
  for (int i = 0; i < MF; ++i)
#pragma unroll
    for (int j = 0; j < NF; ++j) acc[i][j] = (f32x4)0.f;

  // staging pointers: set s -> (A or B, k-half kk, 16-row chunk ch);
  // lane (lm, quad) loads exactly its MFMA fragment 16B.
  const ushortT* gp[SPW];
  ushortT* ld[SPW];
#pragma unroll
  for (int i = 0; i < SPW; ++i) {
    const int s = wave * SPW + i;
    const ushortT* base;
    int row, kof;
    if (s < SETS_A) {
      const int kk = s / CHA, ch = s % CHA;
      base = A; row = bm + ch * 16 + lm; kof = kk * 32;
    } else {
      const int s2 = s - SETS_A;
      const int kk = s2 / CHB, ch = s2 % CHB;
      base = BT; row = bn + ch * 16 + lm; kof = kk * 32;
    }
    gp[i] = base + (size_t)row * K + kof + quad * 8;
    ld[i] = &Ls[s * 512 + lane * 8];
  }

  uint4 rg[SPW];
#define GLOAD(k0)                                        \
  {                                                      \
    _Pragma("unroll") for (int i = 0; i < SPW; ++i)      \
        rg[i] = *(const uint4*)(gp[i] + (k0));           \
  }
#define SWRITE()                                         \
  {                                                      \
    _Pragma("unroll") for (int i = 0; i < SPW; ++i)      \
        *(uint4*)ld[i] = rg[i];                          \
  }

  // prologue: stage tile 0
  GLOAD(0);
  SWRITE();
  __syncthreads();

  for (int k0 = BK; k0 <= K; k0 += BK) {
    const bool more = (k0 < K);
    if (more) GLOAD(k0);  // loads in flight across the whole compute phase

#pragma unroll
    for (int kk = 0; kk < KI; ++kk) {
      const ushortT* ab = &Ls[(kk * CHA + (wr >> 4)) * 512 + lane * 8];
      const ushortT* bb = &Ls[(size_t)TM * BK + (kk * CHB + (wc >> 4)) * 512 + lane * 8];
      short8 af[MF], bf[NF];
#pragma unroll
      for (int mt = 0; mt < MF; ++mt) af[mt] = *(const short8*)(ab + mt * 512);
#pragma unroll
      for (int nt = 0; nt < NF; ++nt) bf[nt] = *(const short8*)(bb + nt * 512);
#pragma unroll
      for (int mt = 0; mt < MF; ++mt)
#pragma unroll
        for (int nt = 0; nt < NF; ++nt)
          acc[mt][nt] = __builtin_amdgcn_mfma_f32_16x16x32_bf16(af[mt], bf[nt], acc[mt][nt], 0, 0, 0);
    }

    if (more) {
      __syncthreads();  // all waves done reading Ls
      SWRITE();         // vmcnt wait lands here, after the MFMA work
      __syncthreads();  // writes visible before next compute phase
    }
  }

  // C/D layout: col = lane&15, row = quad*4 + reg
  if (MODE == EP_LOSS) {
    float lsum = 0.f;
#pragma unroll
    for (int mt = 0; mt < MF; ++mt) {
#pragma unroll
      for (int r = 0; r < 4; ++r) {
        const int row = bm + wr + mt * 16 + quad * 4 + r;
        const float w = wrow[row];
        const ushortT* xr = xa + (size_t)row * N;
        float rs = 0.f;
#pragma unroll
        for (int nt = 0; nt < NF; ++nt) {
          const int col = bn + wc + nt * 16 + lm;
          const float d = bf2f(xr[col]) - (acc[mt][nt][r] + bias[col]);
          rs = fmaf(d, d, rs);
        }
        lsum = fmaf(w, rs, lsum);
      }
    }
    __syncthreads();
    red[t] = lsum;
    __syncthreads();
    for (int st = 128; st > 0; st >>= 1) {
      if (t < st) red[t] += red[t + st];
      __syncthreads();
    }
    if (t == 0) atomicAdd(out, red[0] * (1.0f / (float)NROWS));
  } else {
#pragma unroll
    for (int mt = 0; mt < MF; ++mt)
#pragma unroll
      for (int r = 0; r < 4; ++r) {
        const int row = bm + wr + mt * 16 + quad * 4 + r;
#pragma unroll
        for (int nt = 0; nt < NF; ++nt) {
          const int col = bn + wc + nt * 16 + lm;
          float v = acc[mt][nt][r] + bias[col];
          if (MODE == EP_RELU) v = fmaxf(v, 0.f);
          C[(size_t)row * N + col] = f2bf(v);
        }
      }
  }
#undef GLOAD
#undef SWRITE
}

// Frozen-mask apply on raw pre-activations U (rows x 1024 bf16):
// rows < 4096 (neighbors): out = (U[center_row] > 0) ? U : 0
// rows >= 4096 (centers):  out = relu(U)
__global__ __launch_bounds__(256) void mask_apply(
    const ushortT* __restrict__ U, ushortT* __restrict__ outp) {
  const int i4 = (blockIdx.x * 256 + threadIdx.x) * 4;
  const int r = i4 >> 10;
  const int c = i4 & 1023;
  ushort4 u = *(const ushort4*)(U + i4);
  ushort4 o;
  if (r < NROWS) {
    const ushort4 m = *(const ushort4*)(U + (((size_t)(NROWS + (r >> 5))) << 10) + c);
    o.x = ((short)m.x > 0) ? u.x : 0;
    o.y = ((short)m.y > 0) ? u.y : 0;
    o.z = ((short)m.z > 0) ? u.z : 0;
    o.w = ((short)m.w > 0) ? u.w : 0;
  } else {
    o.x = ((short)u.x > 0) ? u.x : 0;
    o.y = ((short)u.y > 0) ? u.y : 0;
    o.z = ((short)u.z > 0) ? u.z : 0;
    o.w = ((short)u.w > 0) ? u.w : 0;
  }
  *(ushort4*)(outp + i4) = o;
}

// Fused prep: x fp32 -> bf16 A_enc; per-(b,n) weights from dist^2; zero out[0].
__global__ __launch_bounds__(256) void prep_kernel(
    const float* __restrict__ x_c, const float* __restrict__ x_nn,
    ushortT* __restrict__ A_enc, float* __restrict__ wbuf, float* __restrict__ out) {
  const int i = blockIdx.x;
  const int t = threadIdx.x;
  if (i < NROWS) {
    const float* src = x_nn + (size_t)i * D_DIM;
    const float* ctr = x_c + (size_t)(i >> 5) * D_DIM;
    ushortT* dst = A_enc + (size_t)i * D_DIM;
    float s = 0.f;
    for (int d = t * 4; d < D_DIM; d += 1024) {
      const float4 v = *(const float4*)(src + d);
      const float4 c = *(const float4*)(ctr + d);
      ushort4 o;
      o.x = f2bf(v.x); o.y = f2bf(v.y); o.z = f2bf(v.z); o.w = f2bf(v.w);
      *(ushort4*)(dst + d) = o;
      const float dx = v.x - c.x, dy = v.y - c.y, dz = v.z - c.z, dw = v.w - c.w;
      s += dx * dx + dy * dy + dz * dz + dw * dw;
    }
    __shared__ float red[256];
    red[t] = s;
    __syncthreads();
    for (int st = 128; st > 0; st >>= 1) {
      if (t < st) red[t] += red[t + st];
      __syncthreads();
    }
    if (t == 0) {
      wbuf[i] = (red[0] > 1e-24f) ? 1.0f : 0.5f;
      if (i == 0) out[0] = 0.f;
    }
  } else {
    const int r = i - NROWS;
    const float* src = x_c + (size_t)r * D_DIM;
    ushortT* dst = A_enc + (size_t)i * D_DIM;
    for (int d = t * 4; d < D_DIM; d += 1024) {
      const float4 v = *(const float4*)(src + d);
      ushort4 o;
      o.x = f2bf(v.x); o.y = f2bf(v.y); o.z = f2bf(v.z); o.w = f2bf(v.w);
      *(ushort4*)(dst + d) = o;
    }
  }
}

// Batched transpose+cast of all six weights: W (KxN f32) -> WT (NxK bf16).
__global__ __launch_bounds__(256) void trans_all(
    const float* __restrict__ We1, const float* __restrict__ We2,
    const float* __restrict__ We3, const float* __restrict__ Wd1,
    const float* __restrict__ Wd2, const float* __restrict__ Wd3,
    ushortT* __restrict__ We1T, ushortT* __restrict__ We2T,
    ushortT* __restrict__ We3T, ushortT* __restrict__ Wd1T,
    ushortT* __restrict__ Wd2T, ushortT* __restrict__ Wd3T) {
  const int b = blockIdx.x;
  const float* W; ushortT* WT; int K, N, loc;
  if (b < 3072)      { W = We1; WT = We1T; K = 3072; N = 1024; loc = b; }
  else if (b < 4096) { W = We2; WT = We2T; K = 1024; N = 1024; loc = b - 3072; }
  else if (b < 4128) { W = We3; WT = We3T; K = 1024; N = 32;   loc = b - 4096; }
  else if (b < 4160) { W = Wd1; WT = Wd1T; K = 32;   N = 1024; loc = b - 4128; }
  else if (b < 5184) { W = Wd2; WT = Wd2T; K = 1024; N = 1024; loc = b - 4160; }
  else               { W = Wd3; WT = Wd3T; K = 1024; N = 3072; loc = b - 5184; }
  const int ntiles = N >> 5;
  const int n0 = (loc % ntiles) * 32;
  const int k0 = (loc / ntiles) * 32;
  __shared__ float tile[32][33];
  const int tx = threadIdx.x & 31;
  const int ty = threadIdx.x >> 5;
  for (int i = ty; i < 32; i += 8)
    tile[i][tx] = W[(size_t)(k0 + i) * N + n0 + tx];
  __syncthreads();
  for (int i = ty; i < 32; i += 8)
    WT[(size_t)(n0 + i) * K + k0 + tx] = f2bf(tile[tx][i]);
}

extern "C" void kernel_launch(void* const* d_in, const int* in_sizes, int n_in,
                              void* d_out, int out_size, void* d_ws, size_t ws_size,
                              hipStream_t stream) {
  const float* x_c = (const float*)d_in[0];
  const float* x_nn = (const float*)d_in[1];
  const float* We1 = (const float*)d_in[2];
  const float* be1 = (const float*)d_in[3];
  const float* We2 = (const float*)d_in[4];
  const float* be2 = (const float*)d_in[5];
  const float* We3 = (const float*)d_in[6];
  const float* be3 = (const float*)d_in[7];
  const float* Wd1 = (const float*)d_in[8];
  const float* bd1 = (const float*)d_in[9];
  const float* Wd2 = (const float*)d_in[10];
  const float* bd2 = (const float*)d_in[11];
  const float* Wd3 = (const float*)d_in[12];
  const float* bd3 = (const float*)d_in[13];
  float* out = (float*)d_out;

  char* p = (char*)d_ws;
  auto alloc = [&](size_t bytes) {
    char* r = p;
    p += (bytes + 255) & ~(size_t)255;
    return r;
  };
  ushortT* We1T = (ushortT*)alloc((size_t)H_DIM * D_DIM * 2);
  ushortT* We2T = (ushortT*)alloc((size_t)H_DIM * H_DIM * 2);
  ushortT* We3T = (ushortT*)alloc((size_t)Z_DIM * H_DIM * 2);
  ushortT* Wd1T = (ushortT*)alloc((size_t)H_DIM * Z_DIM * 2);
  ushortT* Wd2T = (ushortT*)alloc((size_t)H_DIM * H_DIM * 2);
  ushortT* Wd3T = (ushortT*)alloc((size_t)D_DIM * H_DIM * 2);
  ushortT* A_enc = (ushortT*)alloc((size_t)MENC * D_DIM * 2);
  ushortT* bufX = (ushortT*)alloc((size_t)MENC * H_DIM * 2);  // h1 / U1 / U2
  ushortT* bufY = (ushortT*)alloc((size_t)MENC * H_DIM * 2);  // h2 / A2 / t2
  ushortT* z = (ushortT*)alloc((size_t)MENC * Z_DIM * 2);
  float* wbuf = (float*)alloc((size_t)NROWS * 4);

  const dim3 blk(256);
  const float* nofp = nullptr;
  const ushortT* nobf = nullptr;

  // x -> bf16, per-neighbor weights, zero loss accumulator; weights -> bf16^T
  prep_kernel<<<dim3(MENC), blk, 0, stream>>>(x_c, x_nn, A_enc, wbuf, out);
  trans_all<<<dim3(8256), blk, 0, stream>>>(We1, We2, We3, Wd1, Wd2, Wd3,
                                            We1T, We2T, We3T, Wd1T, Wd2T, Wd3T);

  // encoder on [x_nn; x_c] (4224 rows)
  gemm_rp<EP_RELU, 128, 128, 64><<<dim3(8, 33), blk, 0, stream>>>(
      A_enc, We1T, be1, bufX, MENC, H_DIM, D_DIM, nobf, nofp, nullptr);
  gemm_rp<EP_RELU, 128, 128, 64><<<dim3(8, 33), blk, 0, stream>>>(
      bufX, We2T, be2, bufY, MENC, H_DIM, H_DIM, nobf, nofp, nullptr);
  // z = h2 @ We3 + be3 (skinny N=32; latency hidden in-block)
  gemm_rp<EP_BIAS, 128, 32, 64><<<dim3(1, 33), blk, 0, stream>>>(
      bufY, We3T, be3, z, MENC, Z_DIM, H_DIM, nobf, nofp, nullptr);

  // linearized decoder with frozen center masks (exact for ReLU MLP):
  // U1 = [z_nn; z_c] @ Wd1 + bd1 (raw pre-acts, all rows; K=32 single iter)
  gemm_rp<EP_BIAS, 128, 128, 32><<<dim3(8, 33), blk, 0, stream>>>(
      z, Wd1T, bd1, bufX, MENC, H_DIM, Z_DIM, nobf, nofp, nullptr);
  // A2 = mask1 .* U1 (neighbors), relu(U1) (centers)
  mask_apply<<<dim3((MENC * H_DIM) / 1024), blk, 0, stream>>>(bufX, bufY);
  // U2 = A2 @ Wd2 + bd2 (raw, all rows)
  gemm_rp<EP_BIAS, 128, 128, 64><<<dim3(8, 33), blk, 0, stream>>>(
      bufY, Wd2T, bd2, bufX, MENC, H_DIM, H_DIM, nobf, nofp, nullptr);
  // t2 = mask2 .* U2 (neighbor rows only)
  mask_apply<<<dim3((NROWS * H_DIM) / 1024), blk, 0, stream>>>(bufX, bufY);
  // loss GEMM: pred = t2 @ Wd3 + bd3, fused weighted-SSE vs bf16 x_nn
  gemm_rp<EP_LOSS, 128, 128, 64><<<dim3(24, 32), blk, 0, stream>>>(
      bufY, Wd3T, bd3, nullptr, NROWS, D_DIM, H_DIM, A_enc, wbuf, out);
}

// Round 6
// 743.434 us; speedup vs baseline: 1.0002x; 1.0002x over previous
//
#include <hip/hip_runtime.h>
#include <math.h>

#define D_DIM 3072
#define H_DIM 1024
#define Z_DIM 32
#define BATCH 128
#define NNEI 32
#define NROWS (BATCH * NNEI) /* 4096 */
#define MENC (NROWS + BATCH) /* 4224 */

typedef __attribute__((ext_vector_type(8))) short short8;
typedef __attribute__((ext_vector_type(4))) float f32x4;
typedef unsigned short ushortT;

__device__ __forceinline__ unsigned short f2bf(float f) {
  union { float f; unsigned int u; } v; v.f = f;
  unsigned int r = v.u + 0x7FFFu + ((v.u >> 16) & 1u);
  return (unsigned short)(r >> 16);
}
__device__ __forceinline__ float bf2f(unsigned short b) {
  union { unsigned int u; float f; } v; v.u = ((unsigned int)b) << 16;
  return v.f;
}

enum { EP_RELU = 0, EP_BIAS = 1, EP_LOSS = 2 };

// bf16 MFMA GEMM, global->VGPR->ds_write staging (m93-style), depth-2
// register prefetch, double-buffered LDS, one barrier per K-iter.
// The vmcnt wait for tile k+1's loads lands at its ds_write, ~2 compute
// phases after issue -> global latency hidden inside a single block.
// __launch_bounds__(256,2) caps VGPRs at 256 so nothing spills (R5 lesson:
// default cap was 88 -> scratch catastrophe).
// A: MxK bf16 row-major, BT: NxK bf16. Tile TM x TN, 4 waves 2x2,
// wave tile (TM/2)x(TN/2) via mfma_f32_16x16x32_bf16. M%TM==0, N%TN==0,
// K%BK==0.
template <int MODE, int TM, int TN, int BK>
__global__ __launch_bounds__(256, 2) void gemm_pf(
    const ushortT* __restrict__ A, const ushortT* __restrict__ BT,
    const float* __restrict__ bias, ushortT* __restrict__ C,
    int M, int N, int K,
    const ushortT* __restrict__ xa,    // EP_LOSS: M x N bf16 (x_nn)
    const float* __restrict__ wrow,    // EP_LOSS: per-row weight
    float* __restrict__ out) {
  constexpr int MF = TM / 32;
  constexpr int NF = TN / 32;
  constexpr int KI = BK / 32;
  constexpr int CHA = TM / 16;
  constexpr int CHB = TN / 16;
  constexpr int SETS_A = KI * CHA;
  constexpr int SETS = KI * (CHA + CHB);
  constexpr int SPW = SETS / 4;            // staging 16B-sets per wave
  constexpr int BUFE = (TM + TN) * BK;     // elements per LDS buffer

  __shared__ __align__(16) ushortT Ls[2][BUFE];
  __shared__ float red[256];

  const int t = threadIdx.x;
  const int wave = t >> 6;
  const int lane = t & 63;
  const int quad = lane >> 4;
  const int lm = lane & 15;
  const int bm = blockIdx.y * TM;
  const int bn = blockIdx.x * TN;
  const int wr = (wave >> 1) * (TM / 2);
  const int wc = (wave & 1) * (TN / 2);

  f32x4 acc[MF][NF];
#pragma unroll
  for (int i = 0; i < MF; ++i)
#pragma unroll
    for (int j = 0; j < NF; ++j) acc[i][j] = (f32x4)0.f;

  // staging set s: A sets s = kk*CHA + ch (rows bm+ch*16+lm, k kk*32+quad*8);
  // then B sets. Lane's 16B is exactly its MFMA fragment slot.
  const ushortT* gp[SPW];
  ushortT* lp[SPW];
#pragma unroll
  for (int i = 0; i < SPW; ++i) {
    const int s = wave * SPW + i;
    const ushortT* base;
    int row, kof;
    if (s < SETS_A) {
      const int kk = s / CHA, ch = s % CHA;
      base = A; row = bm + ch * 16 + lm; kof = kk * 32;
    } else {
      const int s2 = s - SETS_A;
      const int kk = s2 / CHB, ch = s2 % CHB;
      base = BT; row = bn + ch * 16 + lm; kof = kk * 32;
    }
    gp[i] = base + (size_t)row * K + kof + quad * 8;
    lp[i] = &Ls[0][s * 512 + lane * 8];
  }

  uint4 rgA[SPW], rgB[SPW];
  auto gload = [&](int k0, uint4* rg) {
#pragma unroll
    for (int i = 0; i < SPW; ++i) rg[i] = *(const uint4*)(gp[i] + k0);
  };
  auto swrite = [&](int b, const uint4* rg) {
#pragma unroll
    for (int i = 0; i < SPW; ++i) *(uint4*)(lp[i] + b * BUFE) = rg[i];
  };
  auto compute = [&](int b) {
#pragma unroll
    for (int kk = 0; kk < KI; ++kk) {
      const ushortT* ab = &Ls[b][(kk * CHA + (wr >> 4)) * 512 + lane * 8];
      const ushortT* bb = &Ls[b][(SETS_A + kk * CHB + (wc >> 4)) * 512 + lane * 8];
      short8 af[MF], bf[NF];
#pragma unroll
      for (int mt = 0; mt < MF; ++mt) af[mt] = *(const short8*)(ab + mt * 512);
#pragma unroll
      for (int nt = 0; nt < NF; ++nt) bf[nt] = *(const short8*)(bb + nt * 512);
#pragma unroll
      for (int mt = 0; mt < MF; ++mt)
#pragma unroll
        for (int nt = 0; nt < NF; ++nt)
          acc[mt][nt] = __builtin_amdgcn_mfma_f32_16x16x32_bf16(af[mt], bf[nt], acc[mt][nt], 0, 0, 0);
    }
  };

  const int n = K / BK;
  // prologue: buf0 = tile0; rgA = tile1; rgB = tile2
  gload(0, rgA);
  swrite(0, rgA);
  if (n > 1) gload(BK, rgA);
  if (n > 2) gload(2 * BK, rgB);
  __syncthreads();

  for (int k = 0; k < n; k += 2) {
    compute(0);  // buf0 = tile k
    if (k + 1 < n) {
      swrite(1, rgA);                       // vmcnt wait: tile k+1 (issued 2 phases ago)
      if (k + 3 < n) gload((k + 3) * BK, rgA);
      __syncthreads();
      compute(1);  // buf1 = tile k+1
      if (k + 2 < n) {
        swrite(0, rgB);
        if (k + 4 < n) gload((k + 4) * BK, rgB);
        __syncthreads();
      }
    }
  }

  // C/D layout: col = lane&15, row = quad*4 + reg
  if (MODE == EP_LOSS) {
    float lsum = 0.f;
#pragma unroll
    for (int mt = 0; mt < MF; ++mt) {
#pragma unroll
      for (int r = 0; r < 4; ++r) {
        const int row = bm + wr + mt * 16 + quad * 4 + r;
        const float w = wrow[row];
        const ushortT* xr = xa + (size_t)row * N;
        float rs = 0.f;
#pragma unroll
        for (int nt = 0; nt < NF; ++nt) {
          const int col = bn + wc + nt * 16 + lm;
          const float d = bf2f(xr[col]) - (acc[mt][nt][r] + bias[col]);
          rs = fmaf(d, d, rs);
        }
        lsum = fmaf(w, rs, lsum);
      }
    }
    __syncthreads();
    red[t] = lsum;
    __syncthreads();
    for (int st = 128; st > 0; st >>= 1) {
      if (t < st) red[t] += red[t + st];
      __syncthreads();
    }
    if (t == 0) atomicAdd(out, red[0] * (1.0f / (float)NROWS));
  } else {
#pragma unroll
    for (int mt = 0; mt < MF; ++mt)
#pragma unroll
      for (int r = 0; r < 4; ++r) {
        const int row = bm + wr + mt * 16 + quad * 4 + r;
#pragma unroll
        for (int nt = 0; nt < NF; ++nt) {
          const int col = bn + wc + nt * 16 + lm;
          float v = acc[mt][nt][r] + bias[col];
          if (MODE == EP_RELU) v = fmaxf(v, 0.f);
          C[(size_t)row * N + col] = f2bf(v);
        }
      }
  }
}

// Frozen-mask apply on raw pre-activations U (rows x 1024 bf16):
// rows < 4096 (neighbors): out = (U[center_row] > 0) ? U : 0
// rows >= 4096 (centers):  out = relu(U)
__global__ __launch_bounds__(256) void mask_apply(
    const ushortT* __restrict__ U, ushortT* __restrict__ outp) {
  const int i4 = (blockIdx.x * 256 + threadIdx.x) * 4;
  const int r = i4 >> 10;
  const int c = i4 & 1023;
  ushort4 u = *(const ushort4*)(U + i4);
  ushort4 o;
  if (r < NROWS) {
    const ushort4 m = *(const ushort4*)(U + (((size_t)(NROWS + (r >> 5))) << 10) + c);
    o.x = ((short)m.x > 0) ? u.x : 0;
    o.y = ((short)m.y > 0) ? u.y : 0;
    o.z = ((short)m.z > 0) ? u.z : 0;
    o.w = ((short)m.w > 0) ? u.w : 0;
  } else {
    o.x = ((short)u.x > 0) ? u.x : 0;
    o.y = ((short)u.y > 0) ? u.y : 0;
    o.z = ((short)u.z > 0) ? u.z : 0;
    o.w = ((short)u.w > 0) ? u.w : 0;
  }
  *(ushort4*)(outp + i4) = o;
}

// Fused prep: x fp32 -> bf16 A_enc; per-(b,n) weights from dist^2; zero out[0].
__global__ __launch_bounds__(256) void prep_kernel(
    const float* __restrict__ x_c, const float* __restrict__ x_nn,
    ushortT* __restrict__ A_enc, float* __restrict__ wbuf, float* __restrict__ out) {
  const int i = blockIdx.x;
  const int t = threadIdx.x;
  if (i < NROWS) {
    const float* src = x_nn + (size_t)i * D_DIM;
    const float* ctr = x_c + (size_t)(i >> 5) * D_DIM;
    ushortT* dst = A_enc + (size_t)i * D_DIM;
    float s = 0.f;
    for (int d = t * 4; d < D_DIM; d += 1024) {
      const float4 v = *(const float4*)(src + d);
      const float4 c = *(const float4*)(ctr + d);
      ushort4 o;
      o.x = f2bf(v.x); o.y = f2bf(v.y); o.z = f2bf(v.z); o.w = f2bf(v.w);
      *(ushort4*)(dst + d) = o;
      const float dx = v.x - c.x, dy = v.y - c.y, dz = v.z - c.z, dw = v.w - c.w;
      s += dx * dx + dy * dy + dz * dz + dw * dw;
    }
    __shared__ float red[256];
    red[t] = s;
    __syncthreads();
    for (int st = 128; st > 0; st >>= 1) {
      if (t < st) red[t] += red[t + st];
      __syncthreads();
    }
    if (t == 0) {
      wbuf[i] = (red[0] > 1e-24f) ? 1.0f : 0.5f;
      if (i == 0) out[0] = 0.f;
    }
  } else {
    const int r = i - NROWS;
    const float* src = x_c + (size_t)r * D_DIM;
    ushortT* dst = A_enc + (size_t)i * D_DIM;
    for (int d = t * 4; d < D_DIM; d += 1024) {
      const float4 v = *(const float4*)(src + d);
      ushort4 o;
      o.x = f2bf(v.x); o.y = f2bf(v.y); o.z = f2bf(v.z); o.w = f2bf(v.w);
      *(ushort4*)(dst + d) = o;
    }
  }
}

// Batched transpose+cast of all six weights: W (KxN f32) -> WT (NxK bf16).
__global__ __launch_bounds__(256) void trans_all(
    const float* __restrict__ We1, const float* __restrict__ We2,
    const float* __restrict__ We3, const float* __restrict__ Wd1,
    const float* __restrict__ Wd2, const float* __restrict__ Wd3,
    ushortT* __restrict__ We1T, ushortT* __restrict__ We2T,
    ushortT* __restrict__ We3T, ushortT* __restrict__ Wd1T,
    ushortT* __restrict__ Wd2T, ushortT* __restrict__ Wd3T) {
  const int b = blockIdx.x;
  const float* W; ushortT* WT; int K, N, loc;
  if (b < 3072)      { W = We1; WT = We1T; K = 3072; N = 1024; loc = b; }
  else if (b < 4096) { W = We2; WT = We2T; K = 1024; N = 1024; loc = b - 3072; }
  else if (b < 4128) { W = We3; WT = We3T; K = 1024; N = 32;   loc = b - 4096; }
  else if (b < 4160) { W = Wd1; WT = Wd1T; K = 32;   N = 1024; loc = b - 4128; }
  else if (b < 5184) { W = Wd2; WT = Wd2T; K = 1024; N = 1024; loc = b - 4160; }
  else               { W = Wd3; WT = Wd3T; K = 1024; N = 3072; loc = b - 5184; }
  const int ntiles = N >> 5;
  const int n0 = (loc % ntiles) * 32;
  const int k0 = (loc / ntiles) * 32;
  __shared__ float tile[32][33];
  const int tx = threadIdx.x & 31;
  const int ty = threadIdx.x >> 5;
  for (int i = ty; i < 32; i += 8)
    tile[i][tx] = W[(size_t)(k0 + i) * N + n0 + tx];
  __syncthreads();
  for (int i = ty; i < 32; i += 8)
    WT[(size_t)(n0 + i) * K + k0 + tx] = f2bf(tile[tx][i]);
}

extern "C" void kernel_launch(void* const* d_in, const int* in_sizes, int n_in,
                              void* d_out, int out_size, void* d_ws, size_t ws_size,
                              hipStream_t stream) {
  const float* x_c = (const float*)d_in[0];
  const float* x_nn = (const float*)d_in[1];
  const float* We1 = (const float*)d_in[2];
  const float* be1 = (const float*)d_in[3];
  const float* We2 = (const float*)d_in[4];
  const float* be2 = (const float*)d_in[5];
  const float* We3 = (const float*)d_in[6];
  const float* be3 = (const float*)d_in[7];
  const float* Wd1 = (const float*)d_in[8];
  const float* bd1 = (const float*)d_in[9];
  const float* Wd2 = (const float*)d_in[10];
  const float* bd2 = (const float*)d_in[11];
  const float* Wd3 = (const float*)d_in[12];
  const float* bd3 = (const float*)d_in[13];
  float* out = (float*)d_out;

  char* p = (char*)d_ws;
  auto alloc = [&](size_t bytes) {
    char* r = p;
    p += (bytes + 255) & ~(size_t)255;
    return r;
  };
  ushortT* We1T = (ushortT*)alloc((size_t)H_DIM * D_DIM * 2);
  ushortT* We2T = (ushortT*)alloc((size_t)H_DIM * H_DIM * 2);
  ushortT* We3T = (ushortT*)alloc((size_t)Z_DIM * H_DIM * 2);
  ushortT* Wd1T = (ushortT*)alloc((size_t)H_DIM * Z_DIM * 2);
  ushortT* Wd2T = (ushortT*)alloc((size_t)H_DIM * H_DIM * 2);
  ushortT* Wd3T = (ushortT*)alloc((size_t)D_DIM * H_DIM * 2);
  ushortT* A_enc = (ushortT*)alloc((size_t)MENC * D_DIM * 2);
  ushortT* bufX = (ushortT*)alloc((size_t)MENC * H_DIM * 2);  // h1 / U1 / U2
  ushortT* bufY = (ushortT*)alloc((size_t)MENC * H_DIM * 2);  // h2 / A2 / t2
  ushortT* z = (ushortT*)alloc((size_t)MENC * Z_DIM * 2);
  float* wbuf = (float*)alloc((size_t)NROWS * 4);

  const dim3 blk(256);
  const float* nofp = nullptr;
  const ushortT* nobf = nullptr;

  // x -> bf16, per-neighbor weights, zero loss accumulator; weights -> bf16^T
  prep_kernel<<<dim3(MENC), blk, 0, stream>>>(x_c, x_nn, A_enc, wbuf, out);
  trans_all<<<dim3(8256), blk, 0, stream>>>(We1, We2, We3, Wd1, Wd2, Wd3,
                                            We1T, We2T, We3T, Wd1T, Wd2T, Wd3T);

  // encoder on [x_nn; x_c] (4224 rows)
  gemm_pf<EP_RELU, 128, 128, 64><<<dim3(8, 33), blk, 0, stream>>>(
      A_enc, We1T, be1, bufX, MENC, H_DIM, D_DIM, nobf, nofp, nullptr);
  gemm_pf<EP_RELU, 128, 128, 64><<<dim3(8, 33), blk, 0, stream>>>(
      bufX, We2T, be2, bufY, MENC, H_DIM, H_DIM, nobf, nofp, nullptr);
  // z = h2 @ We3 + be3 (skinny N=32)
  gemm_pf<EP_BIAS, 128, 32, 64><<<dim3(1, 33), blk, 0, stream>>>(
      bufY, We3T, be3, z, MENC, Z_DIM, H_DIM, nobf, nofp, nullptr);

  // linearized decoder with frozen center masks (exact for ReLU MLP):
  // U1 = [z_nn; z_c] @ Wd1 + bd1 (raw pre-acts; K=32 single iteration)
  gemm_pf<EP_BIAS, 128, 128, 32><<<dim3(8, 33), blk, 0, stream>>>(
      z, Wd1T, bd1, bufX, MENC, H_DIM, Z_DIM, nobf, nofp, nullptr);
  // A2 = mask1 .* U1 (neighbors), relu(U1) (centers)
  mask_apply<<<dim3((MENC * H_DIM) / 1024), blk, 0, stream>>>(bufX, bufY);
  // U2 = A2 @ Wd2 + bd2 (raw, all rows)
  gemm_pf<EP_BIAS, 128, 128, 64><<<dim3(8, 33), blk, 0, stream>>>(
      bufY, Wd2T, bd2, bufX, MENC, H_DIM, H_DIM, nobf, nofp, nullptr);
  // t2 = mask2 .* U2 (neighbor rows only)
  mask_apply<<<dim3((NROWS * H_DIM) / 1024), blk, 0, stream>>>(bufX, bufY);
  // loss GEMM: pred = t2 @ Wd3 + bd3, fused weighted-SSE vs bf16 x_nn
  gemm_pf<EP_LOSS, 128, 128, 64><<<dim3(24, 32), blk, 0, stream>>>(
      bufY, Wd3T, bd3, nullptr, NROWS, D_DIM, H_DIM, A_enc, wbuf, out);
}

// Round 7
// 571.769 us; speedup vs baseline: 1.3005x; 1.3002x over previous
//
#include <hip/hip_runtime.h>
#include <math.h>

#define D_DIM 3072
#define H_DIM 1024
#define Z_DIM 32
#define BATCH 128
#define NNEI 32
#define NROWS (BATCH * NNEI) /* 4096 */
#define MENC (NROWS + BATCH) /* 4224 */

typedef __attribute__((ext_vector_type(8))) short short8;
typedef __attribute__((ext_vector_type(4))) float f32x4;
typedef unsigned short ushortT;

__device__ __forceinline__ unsigned short f2bf(float f) {
  union { float f; unsigned int u; } v; v.f = f;
  unsigned int r = v.u + 0x7FFFu + ((v.u >> 16) & 1u);
  return (unsigned short)(r >> 16);
}
__device__ __forceinline__ float bf2f(unsigned short b) {
  union { unsigned int u; float f; } v; v.u = ((unsigned int)b) << 16;
  return v.f;
}

enum { EP_RELU = 0, EP_BIAS = 1, EP_LOSS = 2 };

// bf16 MFMA GEMM with DIRECT global->VGPR fragment loads (no LDS, no
// barriers in the K-loop). The 16x16x32 MFMA A-fragment for lane
// (lm=lane&15, quad=lane>>4) is A[row0+lm][k+quad*8 .. +8] -- 16 contiguous
// bytes in a row-major matrix, so each fragment is ONE global_load_dwordx4.
// B identical on BT (NxK). Each wave computes a 64x64 (or 64x16 for TN=32)
// tile independently; D rotating register slots pipeline the loads ~D-1
// MFMA-phases ahead (plain VMEM loads queue deeply per wave, unlike
// global_load_lds whose shallow queue + barrier vmcnt(0) drain capped
// R2-R4 at ~750cyc/iter). Slot arrays are indexed ONLY by fully-unrolled
// compile-time indices => SROA keeps them in VGPRs (R5/R6 lesson: pointer-
// param lambdas forced them to scratch).
// A: MxK bf16 row-major, BT: NxK bf16. Block = 4 waves in 2x2 => TM x TN.
// Requires M%TM==0, N%TN==0, K%32==0.
template <int MODE, int TM, int TN, int D>
__global__ __launch_bounds__(256) __attribute__((amdgpu_waves_per_eu(1, 2)))
void gemm_dr(
    const ushortT* __restrict__ A, const ushortT* __restrict__ BT,
    const float* __restrict__ bias, ushortT* __restrict__ C,
    int M, int N, int K,
    const ushortT* __restrict__ xa,    // EP_LOSS: M x N bf16 (x_nn)
    const float* __restrict__ wrow,    // EP_LOSS: per-row weight
    float* __restrict__ out) {
  constexpr int MF = TM / 32;   // 16-row frags per wave
  constexpr int NF = TN / 32;   // 16-col frags per wave

  const int t = threadIdx.x;
  const int wave = t >> 6;
  const int lane = t & 63;
  const int quad = lane >> 4;
  const int lm = lane & 15;
  const int bm = blockIdx.y * TM;
  const int bn = blockIdx.x * TN;
  const int wr = (wave >> 1) * (TM / 2);
  const int wc = (wave & 1) * (TN / 2);

  f32x4 acc[MF][NF];
#pragma unroll
  for (int i = 0; i < MF; ++i)
#pragma unroll
    for (int j = 0; j < NF; ++j) acc[i][j] = (f32x4)0.f;

  // per-fragment global stream pointers
  const ushortT* ap[MF];
  const ushortT* bp[NF];
#pragma unroll
  for (int mt = 0; mt < MF; ++mt)
    ap[mt] = A + (size_t)(bm + wr + mt * 16 + lm) * K + quad * 8;
#pragma unroll
  for (int nt = 0; nt < NF; ++nt)
    bp[nt] = BT + (size_t)(bn + wc + nt * 16 + lm) * K + quad * 8;

  const int nk = K / 32;
  short8 Asl[D][MF], Bsl[D][NF];

  // prologue: fill D slots
#pragma unroll
  for (int d = 0; d < D; ++d) {
    if (d < nk) {
#pragma unroll
      for (int mt = 0; mt < MF; ++mt)
        Asl[d][mt] = *(const short8*)(ap[mt] + (size_t)d * 32);
#pragma unroll
      for (int nt = 0; nt < NF; ++nt)
        Bsl[d][nt] = *(const short8*)(bp[nt] + (size_t)d * 32);
    }
  }

  for (int k0 = 0; k0 < nk; k0 += D) {
#pragma unroll
    for (int d = 0; d < D; ++d) {
      const int k = k0 + d;
      if (k < nk) {
#pragma unroll
        for (int mt = 0; mt < MF; ++mt)
#pragma unroll
          for (int nt = 0; nt < NF; ++nt)
            acc[mt][nt] = __builtin_amdgcn_mfma_f32_16x16x32_bf16(
                Asl[d][mt], Bsl[d][nt], acc[mt][nt], 0, 0, 0);
        const int kn = k + D;
        if (kn < nk) {
#pragma unroll
          for (int mt = 0; mt < MF; ++mt)
            Asl[d][mt] = *(const short8*)(ap[mt] + (size_t)kn * 32);
#pragma unroll
          for (int nt = 0; nt < NF; ++nt)
            Bsl[d][nt] = *(const short8*)(bp[nt] + (size_t)kn * 32);
        }
      }
    }
  }

  // C/D layout: col = lane&15, row = quad*4 + reg
  if (MODE == EP_LOSS) {
    __shared__ float red[256];
    float lsum = 0.f;
#pragma unroll
    for (int mt = 0; mt < MF; ++mt) {
#pragma unroll
      for (int r = 0; r < 4; ++r) {
        const int row = bm + wr + mt * 16 + quad * 4 + r;
        const float w = wrow[row];
        const ushortT* xr = xa + (size_t)row * N;
        float rs = 0.f;
#pragma unroll
        for (int nt = 0; nt < NF; ++nt) {
          const int col = bn + wc + nt * 16 + lm;
          const float d = bf2f(xr[col]) - (acc[mt][nt][r] + bias[col]);
          rs = fmaf(d, d, rs);
        }
        lsum = fmaf(w, rs, lsum);
      }
    }
    __syncthreads();
    red[t] = lsum;
    __syncthreads();
    for (int st = 128; st > 0; st >>= 1) {
      if (t < st) red[t] += red[t + st];
      __syncthreads();
    }
    if (t == 0) atomicAdd(out, red[0] * (1.0f / (float)NROWS));
  } else {
#pragma unroll
    for (int mt = 0; mt < MF; ++mt)
#pragma unroll
      for (int r = 0; r < 4; ++r) {
        const int row = bm + wr + mt * 16 + quad * 4 + r;
#pragma unroll
        for (int nt = 0; nt < NF; ++nt) {
          const int col = bn + wc + nt * 16 + lm;
          float v = acc[mt][nt][r] + bias[col];
          if (MODE == EP_RELU) v = fmaxf(v, 0.f);
          C[(size_t)row * N + col] = f2bf(v);
        }
      }
  }
}

// Frozen-mask apply on raw pre-activations U (rows x 1024 bf16):
// rows < 4096 (neighbors): out = (U[center_row] > 0) ? U : 0
// rows >= 4096 (centers):  out = relu(U)
__global__ __launch_bounds__(256) void mask_apply(
    const ushortT* __restrict__ U, ushortT* __restrict__ outp) {
  const int i4 = (blockIdx.x * 256 + threadIdx.x) * 4;
  const int r = i4 >> 10;
  const int c = i4 & 1023;
  ushort4 u = *(const ushort4*)(U + i4);
  ushort4 o;
  if (r < NROWS) {
    const ushort4 m = *(const ushort4*)(U + (((size_t)(NROWS + (r >> 5))) << 10) + c);
    o.x = ((short)m.x > 0) ? u.x : 0;
    o.y = ((short)m.y > 0) ? u.y : 0;
    o.z = ((short)m.z > 0) ? u.z : 0;
    o.w = ((short)m.w > 0) ? u.w : 0;
  } else {
    o.x = ((short)u.x > 0) ? u.x : 0;
    o.y = ((short)u.y > 0) ? u.y : 0;
    o.z = ((short)u.z > 0) ? u.z : 0;
    o.w = ((short)u.w > 0) ? u.w : 0;
  }
  *(ushort4*)(outp + i4) = o;
}

// Fused prep: x fp32 -> bf16 A_enc; per-(b,n) weights from dist^2; zero out[0].
__global__ __launch_bounds__(256) void prep_kernel(
    const float* __restrict__ x_c, const float* __restrict__ x_nn,
    ushortT* __restrict__ A_enc, float* __restrict__ wbuf, float* __restrict__ out) {
  const int i = blockIdx.x;
  const int t = threadIdx.x;
  if (i < NROWS) {
    const float* src = x_nn + (size_t)i * D_DIM;
    const float* ctr = x_c + (size_t)(i >> 5) * D_DIM;
    ushortT* dst = A_enc + (size_t)i * D_DIM;
    float s = 0.f;
    for (int d = t * 4; d < D_DIM; d += 1024) {
      const float4 v = *(const float4*)(src + d);
      const float4 c = *(const float4*)(ctr + d);
      ushort4 o;
      o.x = f2bf(v.x); o.y = f2bf(v.y); o.z = f2bf(v.z); o.w = f2bf(v.w);
      *(ushort4*)(dst + d) = o;
      const float dx = v.x - c.x, dy = v.y - c.y, dz = v.z - c.z, dw = v.w - c.w;
      s += dx * dx + dy * dy + dz * dz + dw * dw;
    }
    __shared__ float red[256];
    red[t] = s;
    __syncthreads();
    for (int st = 128; st > 0; st >>= 1) {
      if (t < st) red[t] += red[t + st];
      __syncthreads();
    }
    if (t == 0) {
      wbuf[i] = (red[0] > 1e-24f) ? 1.0f : 0.5f;
      if (i == 0) out[0] = 0.f;
    }
  } else {
    const int r = i - NROWS;
    const float* src = x_c + (size_t)r * D_DIM;
    ushortT* dst = A_enc + (size_t)i * D_DIM;
    for (int d = t * 4; d < D_DIM; d += 1024) {
      const float4 v = *(const float4*)(src + d);
      ushort4 o;
      o.x = f2bf(v.x); o.y = f2bf(v.y); o.z = f2bf(v.z); o.w = f2bf(v.w);
      *(ushort4*)(dst + d) = o;
    }
  }
}

// Batched transpose+cast of all six weights: W (KxN f32) -> WT (NxK bf16).
__global__ __launch_bounds__(256) void trans_all(
    const float* __restrict__ We1, const float* __restrict__ We2,
    const float* __restrict__ We3, const float* __restrict__ Wd1,
    const float* __restrict__ Wd2, const float* __restrict__ Wd3,
    ushortT* __restrict__ We1T, ushortT* __restrict__ We2T,
    ushortT* __restrict__ We3T, ushortT* __restrict__ Wd1T,
    ushortT* __restrict__ Wd2T, ushortT* __restrict__ Wd3T) {
  const int b = blockIdx.x;
  const float* W; ushortT* WT; int K, N, loc;
  if (b < 3072)      { W = We1; WT = We1T; K = 3072; N = 1024; loc = b; }
  else if (b < 4096) { W = We2; WT = We2T; K = 1024; N = 1024; loc = b - 3072; }
  else if (b < 4128) { W = We3; WT = We3T; K = 1024; N = 32;   loc = b - 4096; }
  else if (b < 4160) { W = Wd1; WT = Wd1T; K = 32;   N = 1024; loc = b - 4128; }
  else if (b < 5184) { W = Wd2; WT = Wd2T; K = 1024; N = 1024; loc = b - 4160; }
  else               { W = Wd3; WT = Wd3T; K = 1024; N = 3072; loc = b - 5184; }
  const int ntiles = N >> 5;
  const int n0 = (loc % ntiles) * 32;
  const int k0 = (loc / ntiles) * 32;
  __shared__ float tile[32][33];
  const int tx = threadIdx.x & 31;
  const int ty = threadIdx.x >> 5;
  for (int i = ty; i < 32; i += 8)
    tile[i][tx] = W[(size_t)(k0 + i) * N + n0 + tx];
  __syncthreads();
  for (int i = ty; i < 32; i += 8)
    WT[(size_t)(n0 + i) * K + k0 + tx] = f2bf(tile[tx][i]);
}

extern "C" void kernel_launch(void* const* d_in, const int* in_sizes, int n_in,
                              void* d_out, int out_size, void* d_ws, size_t ws_size,
                              hipStream_t stream) {
  const float* x_c = (const float*)d_in[0];
  const float* x_nn = (const float*)d_in[1];
  const float* We1 = (const float*)d_in[2];
  const float* be1 = (const float*)d_in[3];
  const float* We2 = (const float*)d_in[4];
  const float* be2 = (const float*)d_in[5];
  const float* We3 = (const float*)d_in[6];
  const float* be3 = (const float*)d_in[7];
  const float* Wd1 = (const float*)d_in[8];
  const float* bd1 = (const float*)d_in[9];
  const float* Wd2 = (const float*)d_in[10];
  const float* bd2 = (const float*)d_in[11];
  const float* Wd3 = (const float*)d_in[12];
  const float* bd3 = (const float*)d_in[13];
  float* out = (float*)d_out;

  char* p = (char*)d_ws;
  auto alloc = [&](size_t bytes) {
    char* r = p;
    p += (bytes + 255) & ~(size_t)255;
    return r;
  };
  ushortT* We1T = (ushortT*)alloc((size_t)H_DIM * D_DIM * 2);
  ushortT* We2T = (ushortT*)alloc((size_t)H_DIM * H_DIM * 2);
  ushortT* We3T = (ushortT*)alloc((size_t)Z_DIM * H_DIM * 2);
  ushortT* Wd1T = (ushortT*)alloc((size_t)H_DIM * Z_DIM * 2);
  ushortT* Wd2T = (ushortT*)alloc((size_t)H_DIM * H_DIM * 2);
  ushortT* Wd3T = (ushortT*)alloc((size_t)D_DIM * H_DIM * 2);
  ushortT* A_enc = (ushortT*)alloc((size_t)MENC * D_DIM * 2);
  ushortT* bufX = (ushortT*)alloc((size_t)MENC * H_DIM * 2);  // h1 / U1 / U2
  ushortT* bufY = (ushortT*)alloc((size_t)MENC * H_DIM * 2);  // h2 / A2 / t2
  ushortT* z = (ushortT*)alloc((size_t)MENC * Z_DIM * 2);
  float* wbuf = (float*)alloc((size_t)NROWS * 4);

  const dim3 blk(256);
  const float* nofp = nullptr;
  const ushortT* nobf = nullptr;

  // x -> bf16, per-neighbor weights, zero loss accumulator; weights -> bf16^T
  prep_kernel<<<dim3(MENC), blk, 0, stream>>>(x_c, x_nn, A_enc, wbuf, out);
  trans_all<<<dim3(8256), blk, 0, stream>>>(We1, We2, We3, Wd1, Wd2, Wd3,
                                            We1T, We2T, We3T, Wd1T, Wd2T, Wd3T);

  // encoder on [x_nn; x_c] (4224 rows)
  gemm_dr<EP_RELU, 128, 128, 4><<<dim3(8, 33), blk, 0, stream>>>(
      A_enc, We1T, be1, bufX, MENC, H_DIM, D_DIM, nobf, nofp, nullptr);
  gemm_dr<EP_RELU, 128, 128, 4><<<dim3(8, 33), blk, 0, stream>>>(
      bufX, We2T, be2, bufY, MENC, H_DIM, H_DIM, nobf, nofp, nullptr);
  // z = h2 @ We3 + be3 (skinny N=32; wave tile 64x16)
  gemm_dr<EP_BIAS, 128, 32, 4><<<dim3(1, 33), blk, 0, stream>>>(
      bufY, We3T, be3, z, MENC, Z_DIM, H_DIM, nobf, nofp, nullptr);

  // linearized decoder with frozen center masks (exact for ReLU MLP):
  // U1 = [z_nn; z_c] @ Wd1 + bd1 (raw pre-acts; K=32 -> nk=1)
  gemm_dr<EP_BIAS, 128, 128, 4><<<dim3(8, 33), blk, 0, stream>>>(
      z, Wd1T, bd1, bufX, MENC, H_DIM, Z_DIM, nobf, nofp, nullptr);
  // A2 = mask1 .* U1 (neighbors), relu(U1) (centers)
  mask_apply<<<dim3((MENC * H_DIM) / 1024), blk, 0, stream>>>(bufX, bufY);
  // U2 = A2 @ Wd2 + bd2 (raw, all rows)
  gemm_dr<EP_BIAS, 128, 128, 4><<<dim3(8, 33), blk, 0, stream>>>(
      bufY, Wd2T, bd2, bufX, MENC, H_DIM, H_DIM, nobf, nofp, nullptr);
  // t2 = mask2 .* U2 (neighbor rows only)
  mask_apply<<<dim3((NROWS * H_DIM) / 1024), blk, 0, stream>>>(bufX, bufY);
  // loss GEMM: pred = t2 @ Wd3 + bd3, fused weighted-SSE vs bf16 x_nn
  gemm_dr<EP_LOSS, 128, 128, 4><<<dim3(24, 32), blk, 0, stream>>>(
      bufY, Wd3T, bd3, nullptr, NROWS, D_DIM, H_DIM, A_enc, wbuf, out);
}

// Round 8
// 406.206 us; speedup vs baseline: 1.8305x; 1.4076x over previous
//
#include <hip/hip_runtime.h>
#include <math.h>

#define D_DIM 3072
#define H_DIM 1024
#define Z_DIM 32
#define BATCH 128
#define NNEI 32
#define NROWS (BATCH * NNEI) /* 4096 */
#define MENC (NROWS + BATCH) /* 4224 */

typedef __attribute__((ext_vector_type(8))) short short8;
typedef __attribute__((ext_vector_type(4))) float f32x4;
typedef unsigned short ushortT;

__device__ __forceinline__ unsigned short f2bf(float f) {
  union { float f; unsigned int u; } v; v.f = f;
  unsigned int r = v.u + 0x7FFFu + ((v.u >> 16) & 1u);
  return (unsigned short)(r >> 16);
}
__device__ __forceinline__ float bf2f(unsigned short b) {
  union { unsigned int u; float f; } v; v.u = ((unsigned int)b) << 16;
  return v.f;
}

enum { EP_RELU = 0, EP_BIAS = 1, EP_LOSS = 2 };

// bf16 MFMA GEMM, m93-style staging: plain global->VGPR loads (deep per-wave
// queue), ds_write relay into fragment-order LDS, ds_read_b128 -> MFMA.
// Single-buffer LDS, BK=32, 128 x TN tile, 4 waves 2x2.
// Per iter: barrier; ds_write(rg[k]); barrier; rg=load(k+1); ds_read; MFMA.
// The vmcnt wait for rg[k+1] lands at iter k+1's ds_write -- one full
// compute phase (~16 MFMA + 8 ds_read) after issue, so global latency is
// hidden IN-BLOCK (works at 1 block/CU, unlike global_load_lds whose
// barrier vmcnt(0) drain exposed ~full latency per iter in R2-R4).
// All staging regs are scalar-named uint4 (SROA-safe; R5/R6 lesson: arrays
// passed through lambda pointers went to scratch -> 360MB spill traffic).
// LDS layout (proven R2-R4, 0 bank conflicts): slot s (8 elem/lane-slot) =
// chunk c = s>>6 (16 rows), q8 = (s>>4)&3, lm = s&15; lane (lm,quad) reads
// its MFMA fragment at chunk*512 + lane*8.
// A: MxK bf16 row-major, BT: NxK bf16. M%128==0, N%TN==0, K%32==0.
template <int MODE, int TN>
__global__ __launch_bounds__(256) __attribute__((amdgpu_waves_per_eu(1, 2)))
void gemm_sb(
    const ushortT* __restrict__ A, const ushortT* __restrict__ BT,
    const float* __restrict__ bias, ushortT* __restrict__ C,
    int M, int N, int K,
    const ushortT* __restrict__ xa,    // EP_LOSS: M x N bf16 (x_nn)
    const float* __restrict__ wrow,    // EP_LOSS: per-row weight
    float* __restrict__ out) {
  constexpr int NF = TN / 32;  // 4 (TN=128) or 1 (TN=32)

  __shared__ __align__(16) ushortT As[4096];     // 128 x 32
  __shared__ __align__(16) ushortT Bs[TN * 32];

  const int t = threadIdx.x;
  const int wave = t >> 6;
  const int lane = t & 63;
  const int quad = lane >> 4;
  const int lm = lane & 15;
  const int bm = blockIdx.y * 128;
  const int bn = blockIdx.x * TN;
  const int wr = (wave >> 1) * 64;
  const int wc = (wave & 1) * (TN / 2);

  f32x4 acc[4][NF];
#pragma unroll
  for (int i = 0; i < 4; ++i)
#pragma unroll
    for (int j = 0; j < NF; ++j) acc[i][j] = (f32x4)0.f;

  // A staging: thread t owns LDS slots t and t+256 (16B each, consecutive
  // per lane => cascade-friendly ds_write_b128). Global src for slot s:
  // row = (s>>6)*16 + (s&15), kcol = ((s>>4)&3)*8.
  const int a_r0 = (t >> 6) * 16 + (t & 15);
  const int a_q8 = ((t >> 4) & 3) * 8;
  const ushortT* ga0 = A + (size_t)(bm + a_r0) * K + a_q8;
  const ushortT* ga1 = ga0 + (size_t)64 * K;  // slot t+256 -> +4 chunks = +64 rows
  ushortT* wa0 = As + t * 8;
  ushortT* wa1 = As + t * 8 + 2048;

  // B staging: TN=128 -> same dual-slot scheme; TN=32 -> 128 slots, t<128.
  const ushortT* gb0 = nullptr;
  const ushortT* gb1 = nullptr;
  ushortT* wb0 = nullptr;
  ushortT* wb1 = nullptr;
  bool bact = true;
  if (TN == 128) {
    gb0 = BT + (size_t)(bn + a_r0) * K + a_q8;
    gb1 = gb0 + (size_t)64 * K;
    wb0 = Bs + t * 8;
    wb1 = Bs + t * 8 + 2048;
  } else {
    bact = (t < 128);
    const int s = t & 127;
    const int b_r = (s >> 6) * 16 + (s & 15);
    const int b_q8 = ((s >> 4) & 3) * 8;
    gb0 = BT + (size_t)(bn + b_r) * K + b_q8;
    wb0 = Bs + s * 8;
  }

  // prologue: load tile 0 into registers
  uint4 ra0 = *(const uint4*)ga0;
  uint4 ra1 = *(const uint4*)ga1;
  uint4 rb0 = {0, 0, 0, 0};
  uint4 rb1 = {0, 0, 0, 0};
  if (bact) rb0 = *(const uint4*)gb0;
  if (TN == 128) rb1 = *(const uint4*)gb1;
  ga0 += 32; ga1 += 32;
  gb0 += 32;
  if (TN == 128) gb1 += 32;

  const ushortT* arp = As + (wr >> 4) * 512 + lane * 8;
  const ushortT* brp = Bs + (wc >> 4) * 512 + lane * 8;

  for (int k0 = 0; k0 < K; k0 += 32) {
    __syncthreads();  // prior iteration's LDS reads complete
    *(uint4*)wa0 = ra0;   // vmcnt wait for rg (issued one compute phase ago)
    *(uint4*)wa1 = ra1;
    if (bact) *(uint4*)wb0 = rb0;
    if (TN == 128) *(uint4*)wb1 = rb1;
    __syncthreads();  // tile visible to all waves

    if (k0 + 32 < K) {  // issue next tile's loads BEFORE the compute phase
      ra0 = *(const uint4*)ga0;
      ra1 = *(const uint4*)ga1;
      if (bact) rb0 = *(const uint4*)gb0;
      if (TN == 128) rb1 = *(const uint4*)gb1;
      ga0 += 32; ga1 += 32;
      gb0 += 32;
      if (TN == 128) gb1 += 32;
    }

    short8 af[4], bf[NF];
#pragma unroll
    for (int mt = 0; mt < 4; ++mt) af[mt] = *(const short8*)(arp + mt * 512);
#pragma unroll
    for (int nt = 0; nt < NF; ++nt) bf[nt] = *(const short8*)(brp + nt * 512);
#pragma unroll
    for (int mt = 0; mt < 4; ++mt)
#pragma unroll
      for (int nt = 0; nt < NF; ++nt)
        acc[mt][nt] = __builtin_amdgcn_mfma_f32_16x16x32_bf16(af[mt], bf[nt], acc[mt][nt], 0, 0, 0);
  }

  // C/D layout: col = lane&15, row = quad*4 + reg
  if (MODE == EP_LOSS) {
    __shared__ float red[256];
    float lsum = 0.f;
#pragma unroll
    for (int mt = 0; mt < 4; ++mt) {
#pragma unroll
      for (int r = 0; r < 4; ++r) {
        const int row = bm + wr + mt * 16 + quad * 4 + r;
        const float w = wrow[row];
        const ushortT* xr = xa + (size_t)row * N;
        float rs = 0.f;
#pragma unroll
        for (int nt = 0; nt < NF; ++nt) {
          const int col = bn + wc + nt * 16 + lm;
          const float d = bf2f(xr[col]) - (acc[mt][nt][r] + bias[col]);
          rs = fmaf(d, d, rs);
        }
        lsum = fmaf(w, rs, lsum);
      }
    }
    __syncthreads();
    red[t] = lsum;
    __syncthreads();
    for (int st = 128; st > 0; st >>= 1) {
      if (t < st) red[t] += red[t + st];
      __syncthreads();
    }
    if (t == 0) atomicAdd(out, red[0] * (1.0f / (float)NROWS));
  } else {
#pragma unroll
    for (int mt = 0; mt < 4; ++mt)
#pragma unroll
      for (int r = 0; r < 4; ++r) {
        const int row = bm + wr + mt * 16 + quad * 4 + r;
#pragma unroll
        for (int nt = 0; nt < NF; ++nt) {
          const int col = bn + wc + nt * 16 + lm;
          float v = acc[mt][nt][r] + bias[col];
          if (MODE == EP_RELU) v = fmaxf(v, 0.f);
          C[(size_t)row * N + col] = f2bf(v);
        }
      }
  }
}

// Frozen-mask apply on raw pre-activations U (rows x 1024 bf16):
// rows < 4096 (neighbors): out = (U[center_row] > 0) ? U : 0
// rows >= 4096 (centers):  out = relu(U)
__global__ __launch_bounds__(256) void mask_apply(
    const ushortT* __restrict__ U, ushortT* __restrict__ outp) {
  const int i4 = (blockIdx.x * 256 + threadIdx.x) * 4;
  const int r = i4 >> 10;
  const int c = i4 & 1023;
  ushort4 u = *(const ushort4*)(U + i4);
  ushort4 o;
  if (r < NROWS) {
    const ushort4 m = *(const ushort4*)(U + (((size_t)(NROWS + (r >> 5))) << 10) + c);
    o.x = ((short)m.x > 0) ? u.x : 0;
    o.y = ((short)m.y > 0) ? u.y : 0;
    o.z = ((short)m.z > 0) ? u.z : 0;
    o.w = ((short)m.w > 0) ? u.w : 0;
  } else {
    o.x = ((short)u.x > 0) ? u.x : 0;
    o.y = ((short)u.y > 0) ? u.y : 0;
    o.z = ((short)u.z > 0) ? u.z : 0;
    o.w = ((short)u.w > 0) ? u.w : 0;
  }
  *(ushort4*)(outp + i4) = o;
}

// Fused prep: x fp32 -> bf16 A_enc; per-(b,n) weights from dist^2; zero out[0].
__global__ __launch_bounds__(256) void prep_kernel(
    const float* __restrict__ x_c, const float* __restrict__ x_nn,
    ushortT* __restrict__ A_enc, float* __restrict__ wbuf, float* __restrict__ out) {
  const int i = blockIdx.x;
  const int t = threadIdx.x;
  if (i < NROWS) {
    const float* src = x_nn + (size_t)i * D_DIM;
    const float* ctr = x_c + (size_t)(i >> 5) * D_DIM;
    ushortT* dst = A_enc + (size_t)i * D_DIM;
    float s = 0.f;
    for (int d = t * 4; d < D_DIM; d += 1024) {
      const float4 v = *(const float4*)(src + d);
      const float4 c = *(const float4*)(ctr + d);
      ushort4 o;
      o.x = f2bf(v.x); o.y = f2bf(v.y); o.z = f2bf(v.z); o.w = f2bf(v.w);
      *(ushort4*)(dst + d) = o;
      const float dx = v.x - c.x, dy = v.y - c.y, dz = v.z - c.z, dw = v.w - c.w;
      s += dx * dx + dy * dy + dz * dz + dw * dw;
    }
    __shared__ float red[256];
    red[t] = s;
    __syncthreads();
    for (int st = 128; st > 0; st >>= 1) {
      if (t < st) red[t] += red[t + st];
      __syncthreads();
    }
    if (t == 0) {
      wbuf[i] = (red[0] > 1e-24f) ? 1.0f : 0.5f;
      if (i == 0) out[0] = 0.f;
    }
  } else {
    const int r = i - NROWS;
    const float* src = x_c + (size_t)r * D_DIM;
    ushortT* dst = A_enc + (size_t)i * D_DIM;
    for (int d = t * 4; d < D_DIM; d += 1024) {
      const float4 v = *(const float4*)(src + d);
      ushort4 o;
      o.x = f2bf(v.x); o.y = f2bf(v.y); o.z = f2bf(v.z); o.w = f2bf(v.w);
      *(ushort4*)(dst + d) = o;
    }
  }
}

// Batched transpose+cast of all six weights: W (KxN f32) -> WT (NxK bf16).
__global__ __launch_bounds__(256) void trans_all(
    const float* __restrict__ We1, const float* __restrict__ We2,
    const float* __restrict__ We3, const float* __restrict__ Wd1,
    const float* __restrict__ Wd2, const float* __restrict__ Wd3,
    ushortT* __restrict__ We1T, ushortT* __restrict__ We2T,
    ushortT* __restrict__ We3T, ushortT* __restrict__ Wd1T,
    ushortT* __restrict__ Wd2T, ushortT* __restrict__ Wd3T) {
  const int b = blockIdx.x;
  const float* W; ushortT* WT; int K, N, loc;
  if (b < 3072)      { W = We1; WT = We1T; K = 3072; N = 1024; loc = b; }
  else if (b < 4096) { W = We2; WT = We2T; K = 1024; N = 1024; loc = b - 3072; }
  else if (b < 4128) { W = We3; WT = We3T; K = 1024; N = 32;   loc = b - 4096; }
  else if (b < 4160) { W = Wd1; WT = Wd1T; K = 32;   N = 1024; loc = b - 4128; }
  else if (b < 5184) { W = Wd2; WT = Wd2T; K = 1024; N = 1024; loc = b - 4160; }
  else               { W = Wd3; WT = Wd3T; K = 1024; N = 3072; loc = b - 5184; }
  const int ntiles = N >> 5;
  const int n0 = (loc % ntiles) * 32;
  const int k0 = (loc / ntiles) * 32;
  __shared__ float tile[32][33];
  const int tx = threadIdx.x & 31;
  const int ty = threadIdx.x >> 5;
  for (int i = ty; i < 32; i += 8)
    tile[i][tx] = W[(size_t)(k0 + i) * N + n0 + tx];
  __syncthreads();
  for (int i = ty; i < 32; i += 8)
    WT[(size_t)(n0 + i) * K + k0 + tx] = f2bf(tile[tx][i]);
}

extern "C" void kernel_launch(void* const* d_in, const int* in_sizes, int n_in,
                              void* d_out, int out_size, void* d_ws, size_t ws_size,
                              hipStream_t stream) {
  const float* x_c = (const float*)d_in[0];
  const float* x_nn = (const float*)d_in[1];
  const float* We1 = (const float*)d_in[2];
  const float* be1 = (const float*)d_in[3];
  const float* We2 = (const float*)d_in[4];
  const float* be2 = (const float*)d_in[5];
  const float* We3 = (const float*)d_in[6];
  const float* be3 = (const float*)d_in[7];
  const float* Wd1 = (const float*)d_in[8];
  const float* bd1 = (const float*)d_in[9];
  const float* Wd2 = (const float*)d_in[10];
  const float* bd2 = (const float*)d_in[11];
  const float* Wd3 = (const float*)d_in[12];
  const float* bd3 = (const float*)d_in[13];
  float* out = (float*)d_out;

  char* p = (char*)d_ws;
  auto alloc = [&](size_t bytes) {
    char* r = p;
    p += (bytes + 255) & ~(size_t)255;
    return r;
  };
  ushortT* We1T = (ushortT*)alloc((size_t)H_DIM * D_DIM * 2);
  ushortT* We2T = (ushortT*)alloc((size_t)H_DIM * H_DIM * 2);
  ushortT* We3T = (ushortT*)alloc((size_t)Z_DIM * H_DIM * 2);
  ushortT* Wd1T = (ushortT*)alloc((size_t)H_DIM * Z_DIM * 2);
  ushortT* Wd2T = (ushortT*)alloc((size_t)H_DIM * H_DIM * 2);
  ushortT* Wd3T = (ushortT*)alloc((size_t)D_DIM * H_DIM * 2);
  ushortT* A_enc = (ushortT*)alloc((size_t)MENC * D_DIM * 2);
  ushortT* bufX = (ushortT*)alloc((size_t)MENC * H_DIM * 2);  // h1 / U1 / U2
  ushortT* bufY = (ushortT*)alloc((size_t)MENC * H_DIM * 2);  // h2 / A2 / t2
  ushortT* z = (ushortT*)alloc((size_t)MENC * Z_DIM * 2);
  float* wbuf = (float*)alloc((size_t)NROWS * 4);

  const dim3 blk(256);
  const float* nofp = nullptr;
  const ushortT* nobf = nullptr;

  // x -> bf16, per-neighbor weights, zero loss accumulator; weights -> bf16^T
  prep_kernel<<<dim3(MENC), blk, 0, stream>>>(x_c, x_nn, A_enc, wbuf, out);
  trans_all<<<dim3(8256), blk, 0, stream>>>(We1, We2, We3, Wd1, Wd2, Wd3,
                                            We1T, We2T, We3T, Wd1T, Wd2T, Wd3T);

  // encoder on [x_nn; x_c] (4224 rows)
  gemm_sb<EP_RELU, 128><<<dim3(8, 33), blk, 0, stream>>>(
      A_enc, We1T, be1, bufX, MENC, H_DIM, D_DIM, nobf, nofp, nullptr);
  gemm_sb<EP_RELU, 128><<<dim3(8, 33), blk, 0, stream>>>(
      bufX, We2T, be2, bufY, MENC, H_DIM, H_DIM, nobf, nofp, nullptr);
  // z = h2 @ We3 + be3 (skinny N=32; wave tile 64x16)
  gemm_sb<EP_BIAS, 32><<<dim3(1, 33), blk, 0, stream>>>(
      bufY, We3T, be3, z, MENC, Z_DIM, H_DIM, nobf, nofp, nullptr);

  // linearized decoder with frozen center masks (exact for ReLU MLP):
  // U1 = [z_nn; z_c] @ Wd1 + bd1 (raw pre-acts; K=32 -> 1 iter)
  gemm_sb<EP_BIAS, 128><<<dim3(8, 33), blk, 0, stream>>>(
      z, Wd1T, bd1, bufX, MENC, H_DIM, Z_DIM, nobf, nofp, nullptr);
  // A2 = mask1 .* U1 (neighbors), relu(U1) (centers)
  mask_apply<<<dim3((MENC * H_DIM) / 1024), blk, 0, stream>>>(bufX, bufY);
  // U2 = A2 @ Wd2 + bd2 (raw, all rows)
  gemm_sb<EP_BIAS, 128><<<dim3(8, 33), blk, 0, stream>>>(
      bufY, Wd2T, bd2, bufX, MENC, H_DIM, H_DIM, nobf, nofp, nullptr);
  // t2 = mask2 .* U2 (neighbor rows only)
  mask_apply<<<dim3((NROWS * H_DIM) / 1024), blk, 0, stream>>>(bufX, bufY);
  // loss GEMM: pred = t2 @ Wd3 + bd3, fused weighted-SSE vs bf16 x_nn
  gemm_sb<EP_LOSS, 128><<<dim3(24, 32), blk, 0, stream>>>(
      bufY, Wd3T, bd3, nullptr, NROWS, D_DIM, H_DIM, A_enc, wbuf, out);
}

// Round 9
// 403.414 us; speedup vs baseline: 1.8432x; 1.0069x over previous
//
#include <hip/hip_runtime.h>
#include <math.h>

#define D_DIM 3072
#define H_DIM 1024
#define Z_DIM 32
#define BATCH 128
#define NNEI 32
#define NROWS (BATCH * NNEI) /* 4096 */
#define MENC (NROWS + BATCH) /* 4224 */

typedef __attribute__((ext_vector_type(8))) short short8;
typedef __attribute__((ext_vector_type(4))) float f32x4;
typedef unsigned short ushortT;

__device__ __forceinline__ unsigned short f2bf(float f) {
  union { float f; unsigned int u; } v; v.f = f;
  unsigned int r = v.u + 0x7FFFu + ((v.u >> 16) & 1u);
  return (unsigned short)(r >> 16);
}
__device__ __forceinline__ float bf2f(unsigned short b) {
  union { unsigned int u; float f; } v; v.u = ((unsigned int)b) << 16;
  return v.f;
}

enum { EP_RELU = 0, EP_BIAS = 1, EP_LOSS = 2 };

// bf16 MFMA GEMM: global->VGPR->ds_write relay (R8) + DEPTH-2 register
// prefetch + DOUBLE-BUFFERED LDS (one barrier/iter).
// R8 post-mortem: per-iter 1190 cyc = DS-pipe 576 + vmcnt stall (load issued
// only ~1 phase (~400cyc) before its ds_write; HBM latency ~900) + 2 barriers.
// Fix: two parity-indexed register sets (E=even tiles, O=odd) -> each load is
// in flight ~2 iters (>900 cyc) before its ds_write; write tile k+1 into
// buf^1 while computing tile k from buf (write/read overlap on the DS pipe,
// single barrier per iter). Plain VGPR loads are NOT drained at s_barrier
// (AITER s02: vmcnt(2/5/12) across barriers), unlike global_load_lds.
// All staging regs are named scalars (SROA-safe; R5/R6 lesson).
// Barrier safety: every buffer write is preceded by a barrier since that
// buffer's last read, every read by a barrier since its write (see loop).
// A: MxK bf16 row-major, BT: NxK bf16. TM=128, BK=32, 4 waves 2x2.
// M%128==0, N%TN==0, K%32==0.
template <int MODE, int TN>
__global__ __launch_bounds__(256) __attribute__((amdgpu_waves_per_eu(1, 2)))
void gemm_db(
    const ushortT* __restrict__ A, const ushortT* __restrict__ BT,
    const float* __restrict__ bias, ushortT* __restrict__ C,
    int M, int N, int K,
    const ushortT* __restrict__ xa,    // EP_LOSS: M x N bf16 (x_nn)
    const float* __restrict__ wrow,    // EP_LOSS: per-row weight
    float* __restrict__ out) {
  constexpr int NF = TN / 32;  // 4 (TN=128) or 1 (TN=32)

  __shared__ __align__(16) ushortT As[2][4096];
  __shared__ __align__(16) ushortT Bs[2][TN * 32];

  const int t = threadIdx.x;
  const int wave = t >> 6;
  const int lane = t & 63;
  const int quad = lane >> 4;
  const int lm = lane & 15;
  const int bm = blockIdx.y * 128;
  const int bn = blockIdx.x * TN;
  const int wr = (wave >> 1) * 64;
  const int wc = (wave & 1) * (TN / 2);

  f32x4 acc[4][NF];
#pragma unroll
  for (int i = 0; i < 4; ++i)
#pragma unroll
    for (int j = 0; j < NF; ++j) acc[i][j] = (f32x4)0.f;

  // staging: thread t owns A LDS slots t and t+256 (16B each); global src:
  // row = (slot>>6)*16 + (slot&15), kcol = ((slot>>4)&3)*8 (fragment order).
  const int a_r0 = (t >> 6) * 16 + (t & 15);
  const int a_q8 = ((t >> 4) & 3) * 8;
  const ushortT* ga0 = A + (size_t)(bm + a_r0) * K + a_q8;
  const ushortT* ga1 = ga0 + (size_t)64 * K;

  const ushortT* gb0 = nullptr;
  const ushortT* gb1 = nullptr;
  bool bact = true;
  int bslot = t;
  if (TN == 128) {
    gb0 = BT + (size_t)(bn + a_r0) * K + a_q8;
    gb1 = gb0 + (size_t)64 * K;
  } else {
    bact = (t < 128);
    bslot = t & 127;
    const int b_r = (bslot >> 6) * 16 + (bslot & 15);
    const int b_q8 = ((bslot >> 4) & 3) * 8;
    gb0 = BT + (size_t)(bn + b_r) * K + b_q8;
  }

#define LDA(r0, r1, kk)                                   \
  {                                                       \
    r0 = *(const uint4*)(ga0 + (size_t)(kk) * 32);        \
    r1 = *(const uint4*)(ga1 + (size_t)(kk) * 32);        \
  }
#define LDB(r0, r1, kk)                                   \
  {                                                       \
    if (TN == 128) {                                      \
      r0 = *(const uint4*)(gb0 + (size_t)(kk) * 32);      \
      r1 = *(const uint4*)(gb1 + (size_t)(kk) * 32);      \
    } else if (bact) {                                    \
      r0 = *(const uint4*)(gb0 + (size_t)(kk) * 32);      \
    }                                                     \
  }
#define STW(bsel, A0, A1, B0, B1)                         \
  {                                                       \
    *(uint4*)&As[bsel][t * 8] = A0;                       \
    *(uint4*)&As[bsel][t * 8 + 2048] = A1;                \
    if (TN == 128) {                                      \
      *(uint4*)&Bs[bsel][t * 8] = B0;                     \
      *(uint4*)&Bs[bsel][t * 8 + 2048] = B1;              \
    } else if (bact) {                                    \
      *(uint4*)&Bs[bsel][bslot * 8] = B0;                 \
    }                                                     \
  }
#define CMP(bsel)                                                           \
  {                                                                         \
    const ushortT* arp = &As[bsel][(wr >> 4) * 512 + lane * 8];             \
    const ushortT* brp = &Bs[bsel][(wc >> 4) * 512 + lane * 8];             \
    short8 af[4], bf[NF];                                                   \
    _Pragma("unroll") for (int mt = 0; mt < 4; ++mt)                        \
        af[mt] = *(const short8*)(arp + mt * 512);                          \
    _Pragma("unroll") for (int nt = 0; nt < NF; ++nt)                       \
        bf[nt] = *(const short8*)(brp + nt * 512);                          \
    _Pragma("unroll") for (int mt = 0; mt < 4; ++mt)                        \
        _Pragma("unroll") for (int nt = 0; nt < NF; ++nt)                   \
            acc[mt][nt] = __builtin_amdgcn_mfma_f32_16x16x32_bf16(          \
                af[mt], bf[nt], acc[mt][nt], 0, 0, 0);                      \
  }

  const int nk = K / 32;
  uint4 ea0, ea1, eb0 = {0, 0, 0, 0}, eb1 = {0, 0, 0, 0};
  uint4 oa0 = {0, 0, 0, 0}, oa1 = {0, 0, 0, 0};
  uint4 ob0 = {0, 0, 0, 0}, ob1 = {0, 0, 0, 0};

  // prologue: E=tile0 -> write buf0; O=tile1; E reloads tile2
  LDA(ea0, ea1, 0); LDB(eb0, eb1, 0);
  if (nk > 1) { LDA(oa0, oa1, 1); LDB(ob0, ob1, 1); }
  STW(0, ea0, ea1, eb0, eb1);
  if (nk > 2) { LDA(ea0, ea1, 2); LDB(eb0, eb1, 2); }
  __syncthreads();

  for (int k = 0; k < nk; k += 2) {
    if (k + 1 < nk) {
      STW(1, oa0, oa1, ob0, ob1);  // tile k+1 (in flight ~2 iters)
      if (k + 3 < nk) { LDA(oa0, oa1, k + 3); LDB(ob0, ob1, k + 3); }
    }
    CMP(0);  // tile k
    if (k + 1 < nk) {
      __syncthreads();
      if (k + 2 < nk) {
        STW(0, ea0, ea1, eb0, eb1);  // tile k+2
        if (k + 4 < nk) { LDA(ea0, ea1, k + 4); LDB(eb0, eb1, k + 4); }
      }
      CMP(1);  // tile k+1
      if (k + 2 < nk) __syncthreads();
    }
  }
#undef LDA
#undef LDB
#undef STW
#undef CMP

  // C/D layout: col = lane&15, row = quad*4 + reg
  if (MODE == EP_LOSS) {
    __shared__ float red[256];
    float lsum = 0.f;
#pragma unroll
    for (int mt = 0; mt < 4; ++mt) {
#pragma unroll
      for (int r = 0; r < 4; ++r) {
        const int row = bm + wr + mt * 16 + quad * 4 + r;
        const float w = wrow[row];
        const ushortT* xr = xa + (size_t)row * N;
        float rs = 0.f;
#pragma unroll
        for (int nt = 0; nt < NF; ++nt) {
          const int col = bn + wc + nt * 16 + lm;
          const float d = bf2f(xr[col]) - (acc[mt][nt][r] + bias[col]);
          rs = fmaf(d, d, rs);
        }
        lsum = fmaf(w, rs, lsum);
      }
    }
    __syncthreads();
    red[t] = lsum;
    __syncthreads();
    for (int st = 128; st > 0; st >>= 1) {
      if (t < st) red[t] += red[t + st];
      __syncthreads();
    }
    if (t == 0) atomicAdd(out, red[0] * (1.0f / (float)NROWS));
  } else {
#pragma unroll
    for (int mt = 0; mt < 4; ++mt)
#pragma unroll
      for (int r = 0; r < 4; ++r) {
        const int row = bm + wr + mt * 16 + quad * 4 + r;
#pragma unroll
        for (int nt = 0; nt < NF; ++nt) {
          const int col = bn + wc + nt * 16 + lm;
          float v = acc[mt][nt][r] + bias[col];
          if (MODE == EP_RELU) v = fmaxf(v, 0.f);
          C[(size_t)row * N + col] = f2bf(v);
        }
      }
  }
}

// Frozen-mask apply on raw pre-activations U (rows x 1024 bf16):
// rows < 4096 (neighbors): out = (U[center_row] > 0) ? U : 0
// rows >= 4096 (centers):  out = relu(U)
__global__ __launch_bounds__(256) void mask_apply(
    const ushortT* __restrict__ U, ushortT* __restrict__ outp) {
  const int i4 = (blockIdx.x * 256 + threadIdx.x) * 4;
  const int r = i4 >> 10;
  const int c = i4 & 1023;
  ushort4 u = *(const ushort4*)(U + i4);
  ushort4 o;
  if (r < NROWS) {
    const ushort4 m = *(const ushort4*)(U + (((size_t)(NROWS + (r >> 5))) << 10) + c);
    o.x = ((short)m.x > 0) ? u.x : 0;
    o.y = ((short)m.y > 0) ? u.y : 0;
    o.z = ((short)m.z > 0) ? u.z : 0;
    o.w = ((short)m.w > 0) ? u.w : 0;
  } else {
    o.x = ((short)u.x > 0) ? u.x : 0;
    o.y = ((short)u.y > 0) ? u.y : 0;
    o.z = ((short)u.z > 0) ? u.z : 0;
    o.w = ((short)u.w > 0) ? u.w : 0;
  }
  *(ushort4*)(outp + i4) = o;
}

// Fused prep: x fp32 -> bf16 A_enc; per-(b,n) weights from dist^2; zero out[0].
__global__ __launch_bounds__(256) void prep_kernel(
    const float* __restrict__ x_c, const float* __restrict__ x_nn,
    ushortT* __restrict__ A_enc, float* __restrict__ wbuf, float* __restrict__ out) {
  const int i = blockIdx.x;
  const int t = threadIdx.x;
  if (i < NROWS) {
    const float* src = x_nn + (size_t)i * D_DIM;
    const float* ctr = x_c + (size_t)(i >> 5) * D_DIM;
    ushortT* dst = A_enc + (size_t)i * D_DIM;
    float s = 0.f;
    for (int d = t * 4; d < D_DIM; d += 1024) {
      const float4 v = *(const float4*)(src + d);
      const float4 c = *(const float4*)(ctr + d);
      ushort4 o;
      o.x = f2bf(v.x); o.y = f2bf(v.y); o.z = f2bf(v.z); o.w = f2bf(v.w);
      *(ushort4*)(dst + d) = o;
      const float dx = v.x - c.x, dy = v.y - c.y, dz = v.z - c.z, dw = v.w - c.w;
      s += dx * dx + dy * dy + dz * dz + dw * dw;
    }
    __shared__ float red[256];
    red[t] = s;
    __syncthreads();
    for (int st = 128; st > 0; st >>= 1) {
      if (t < st) red[t] += red[t + st];
      __syncthreads();
    }
    if (t == 0) {
      wbuf[i] = (red[0] > 1e-24f) ? 1.0f : 0.5f;
      if (i == 0) out[0] = 0.f;
    }
  } else {
    const int r = i - NROWS;
    const float* src = x_c + (size_t)r * D_DIM;
    ushortT* dst = A_enc + (size_t)i * D_DIM;
    for (int d = t * 4; d < D_DIM; d += 1024) {
      const float4 v = *(const float4*)(src + d);
      ushort4 o;
      o.x = f2bf(v.x); o.y = f2bf(v.y); o.z = f2bf(v.z); o.w = f2bf(v.w);
      *(ushort4*)(dst + d) = o;
    }
  }
}

// Batched transpose+cast of all six weights: W (KxN f32) -> WT (NxK bf16).
__global__ __launch_bounds__(256) void trans_all(
    const float* __restrict__ We1, const float* __restrict__ We2,
    const float* __restrict__ We3, const float* __restrict__ Wd1,
    const float* __restrict__ Wd2, const float* __restrict__ Wd3,
    ushortT* __restrict__ We1T, ushortT* __restrict__ We2T,
    ushortT* __restrict__ We3T, ushortT* __restrict__ Wd1T,
    ushortT* __restrict__ Wd2T, ushortT* __restrict__ Wd3T) {
  const int b = blockIdx.x;
  const float* W; ushortT* WT; int K, N, loc;
  if (b < 3072)      { W = We1; WT = We1T; K = 3072; N = 1024; loc = b; }
  else if (b < 4096) { W = We2; WT = We2T; K = 1024; N = 1024; loc = b - 3072; }
  else if (b < 4128) { W = We3; WT = We3T; K = 1024; N = 32;   loc = b - 4096; }
  else if (b < 4160) { W = Wd1; WT = Wd1T; K = 32;   N = 1024; loc = b - 4128; }
  else if (b < 5184) { W = Wd2; WT = Wd2T; K = 1024; N = 1024; loc = b - 4160; }
  else               { W = Wd3; WT = Wd3T; K = 1024; N = 3072; loc = b - 5184; }
  const int ntiles = N >> 5;
  const int n0 = (loc % ntiles) * 32;
  const int k0 = (loc / ntiles) * 32;
  __shared__ float tile[32][33];
  const int tx = threadIdx.x & 31;
  const int ty = threadIdx.x >> 5;
  for (int i = ty; i < 32; i += 8)
    tile[i][tx] = W[(size_t)(k0 + i) * N + n0 + tx];
  __syncthreads();
  for (int i = ty; i < 32; i += 8)
    WT[(size_t)(n0 + i) * K + k0 + tx] = f2bf(tile[tx][i]);
}

extern "C" void kernel_launch(void* const* d_in, const int* in_sizes, int n_in,
                              void* d_out, int out_size, void* d_ws, size_t ws_size,
                              hipStream_t stream) {
  const float* x_c = (const float*)d_in[0];
  const float* x_nn = (const float*)d_in[1];
  const float* We1 = (const float*)d_in[2];
  const float* be1 = (const float*)d_in[3];
  const float* We2 = (const float*)d_in[4];
  const float* be2 = (const float*)d_in[5];
  const float* We3 = (const float*)d_in[6];
  const float* be3 = (const float*)d_in[7];
  const float* Wd1 = (const float*)d_in[8];
  const float* bd1 = (const float*)d_in[9];
  const float* Wd2 = (const float*)d_in[10];
  const float* bd2 = (const float*)d_in[11];
  const float* Wd3 = (const float*)d_in[12];
  const float* bd3 = (const float*)d_in[13];
  float* out = (float*)d_out;

  char* p = (char*)d_ws;
  auto alloc = [&](size_t bytes) {
    char* r = p;
    p += (bytes + 255) & ~(size_t)255;
    return r;
  };
  ushortT* We1T = (ushortT*)alloc((size_t)H_DIM * D_DIM * 2);
  ushortT* We2T = (ushortT*)alloc((size_t)H_DIM * H_DIM * 2);
  ushortT* We3T = (ushortT*)alloc((size_t)Z_DIM * H_DIM * 2);
  ushortT* Wd1T = (ushortT*)alloc((size_t)H_DIM * Z_DIM * 2);
  ushortT* Wd2T = (ushortT*)alloc((size_t)H_DIM * H_DIM * 2);
  ushortT* Wd3T = (ushortT*)alloc((size_t)D_DIM * H_DIM * 2);
  ushortT* A_enc = (ushortT*)alloc((size_t)MENC * D_DIM * 2);
  ushortT* bufX = (ushortT*)alloc((size_t)MENC * H_DIM * 2);  // h1 / U1 / U2
  ushortT* bufY = (ushortT*)alloc((size_t)MENC * H_DIM * 2);  // h2 / A2 / t2
  ushortT* z = (ushortT*)alloc((size_t)MENC * Z_DIM * 2);
  float* wbuf = (float*)alloc((size_t)NROWS * 4);

  const dim3 blk(256);
  const float* nofp = nullptr;
  const ushortT* nobf = nullptr;

  // x -> bf16, per-neighbor weights, zero loss accumulator; weights -> bf16^T
  prep_kernel<<<dim3(MENC), blk, 0, stream>>>(x_c, x_nn, A_enc, wbuf, out);
  trans_all<<<dim3(8256), blk, 0, stream>>>(We1, We2, We3, Wd1, Wd2, Wd3,
                                            We1T, We2T, We3T, Wd1T, Wd2T, Wd3T);

  // encoder on [x_nn; x_c] (4224 rows)
  gemm_db<EP_RELU, 128><<<dim3(8, 33), blk, 0, stream>>>(
      A_enc, We1T, be1, bufX, MENC, H_DIM, D_DIM, nobf, nofp, nullptr);
  gemm_db<EP_RELU, 128><<<dim3(8, 33), blk, 0, stream>>>(
      bufX, We2T, be2, bufY, MENC, H_DIM, H_DIM, nobf, nofp, nullptr);
  // z = h2 @ We3 + be3 (skinny N=32; wave tile 64x16)
  gemm_db<EP_BIAS, 32><<<dim3(1, 33), blk, 0, stream>>>(
      bufY, We3T, be3, z, MENC, Z_DIM, H_DIM, nobf, nofp, nullptr);

  // linearized decoder with frozen center masks (exact for ReLU MLP):
  // U1 = [z_nn; z_c] @ Wd1 + bd1 (raw pre-acts; K=32 -> 1 iter)
  gemm_db<EP_BIAS, 128><<<dim3(8, 33), blk, 0, stream>>>(
      z, Wd1T, bd1, bufX, MENC, H_DIM, Z_DIM, nobf, nofp, nullptr);
  // A2 = mask1 .* U1 (neighbors), relu(U1) (centers)
  mask_apply<<<dim3((MENC * H_DIM) / 1024), blk, 0, stream>>>(bufX, bufY);
  // U2 = A2 @ Wd2 + bd2 (raw, all rows)
  gemm_db<EP_BIAS, 128><<<dim3(8, 33), blk, 0, stream>>>(
      bufY, Wd2T, bd2, bufX, MENC, H_DIM, H_DIM, nobf, nofp, nullptr);
  // t2 = mask2 .* U2 (neighbor rows only)
  mask_apply<<<dim3((NROWS * H_DIM) / 1024), blk, 0, stream>>>(bufX, bufY);
  // loss GEMM: pred = t2 @ Wd3 + bd3, fused weighted-SSE vs bf16 x_nn
  gemm_db<EP_LOSS, 128><<<dim3(24, 32), blk, 0, stream>>>(
      bufY, Wd3T, bd3, nullptr, NROWS, D_DIM, H_DIM, A_enc, wbuf, out);
}

// Round 10
// 389.085 us; speedup vs baseline: 1.9111x; 1.0368x over previous
//
#include <hip/hip_runtime.h>
#include <math.h>

#define D_DIM 3072
#define H_DIM 1024
#define Z_DIM 32
#define BATCH 128
#define NNEI 32
#define NROWS (BATCH * NNEI) /* 4096 */
#define MENC (NROWS + BATCH) /* 4224 */

typedef __attribute__((ext_vector_type(8))) short short8;
typedef __attribute__((ext_vector_type(4))) float f32x4;
typedef unsigned short ushortT;

__device__ __forceinline__ unsigned short f2bf(float f) {
  union { float f; unsigned int u; } v; v.f = f;
  unsigned int r = v.u + 0x7FFFu + ((v.u >> 16) & 1u);
  return (unsigned short)(r >> 16);
}
__device__ __forceinline__ float bf2f(unsigned short b) {
  union { unsigned int u; float f; } v; v.u = ((unsigned int)b) << 16;
  return v.f;
}

enum { EP_RELU = 0, EP_BIAS = 1, EP_PART = 2, EP_LOSS = 3 };

// bf16 MFMA GEMM, BK=64, global->VGPR->ds_write relay, single-buffer LDS.
// R9 post-mortem: per-BK32-iter cost ~1200 cyc is a latency/overhead floor
// (DS pipe only ~25% busy, MFMA 10%) that neither occupancy nor deeper
// prefetch reduced. BK=64 amortizes the fixed per-iter overhead over 2x
// work (48 iters instead of 96 at K=3072).
// Staging: 8 named uint4/thread (a0..a3, b0..b3) -- SROA-safe (R5/R6: any
// array-through-pointer staging spills to scratch). LDS fragment order per
// k-half kh (4096 elem): chunk c (16 rows) at c*512, lane (lm,quad) fragment
// at lane*8 -- conflict-free b128 writes/reads.
// Per iter: barrier; ds_write(regs); barrier; load(k+1); compute both
// k-halves (2 x [4+NF ds_read_b128, 16/8 MFMA x NF]).
// Split-K: grid.z = S, each covers Ks = K/S (EP_PART stores f32 partials).
// A: MxK bf16 row-major, BT: NxK bf16. M%128==0, N%TN==0, Ks%64==0.
template <int MODE, int TN>
__global__ __launch_bounds__(256) __attribute__((amdgpu_waves_per_eu(1, 2)))
void gemm64(
    const ushortT* __restrict__ A, const ushortT* __restrict__ BT,
    const float* __restrict__ bias, ushortT* __restrict__ C,
    float* __restrict__ P, int M, int N, int K, int Ks,
    const ushortT* __restrict__ xa,    // EP_LOSS: M x N bf16 (x_nn)
    const float* __restrict__ wrow,    // EP_LOSS: per-row weight
    float* __restrict__ out) {
  constexpr int NF = TN / 32;  // 4 (TN=128) or 1 (TN=32)

  __shared__ __align__(16) ushortT As[8192];      // 128 x 64
  __shared__ __align__(16) ushortT Bs[TN * 64];

  const int t = threadIdx.x;
  const int wave = t >> 6;
  const int lane = t & 63;
  const int quad = lane >> 4;
  const int lm = lane & 15;
  const int bm = blockIdx.y * 128;
  const int bn = blockIdx.x * TN;
  const int koff = blockIdx.z * Ks;
  const int wr = (wave >> 1) * 64;
  const int wc = (wave & 1) * (TN / 2);

  f32x4 acc[4][NF];
#pragma unroll
  for (int i = 0; i < 4; ++i)
#pragma unroll
    for (int j = 0; j < NF; ++j) acc[i][j] = (f32x4)0.f;

  // A staging: thread t owns LDS slots {t, t+256, t+512, t+768}:
  //   t      -> kh0, rows (t>>6)*16+(t&15),      k ((t>>4)&3)*8
  //   t+256  -> kh0, rows +64
  //   t+512  -> kh1 (k +32), rows as t
  //   t+768  -> kh1, rows +64
  const int a_r0 = (t >> 6) * 16 + (t & 15);
  const int a_q8 = ((t >> 4) & 3) * 8;
  const ushortT* ga = A + (size_t)(bm + a_r0) * K + koff + a_q8;
  const size_t aK64 = (size_t)64 * K;

  const ushortT* gb = nullptr;
  if (TN == 128) {
    gb = BT + (size_t)(bn + a_r0) * K + koff + a_q8;
  } else {
    // B tile 32x64 = 256 slots, 1/thread: slot t -> kh=t>>7, c=(t>>6)&1
    const int b_r = ((t >> 6) & 1) * 16 + (t & 15);
    const int b_k = (t >> 7) * 32 + ((t >> 4) & 3) * 8;
    gb = BT + (size_t)(bn + b_r) * K + koff + b_k;
  }

  uint4 a0, a1, a2, a3, b0, b1 = {0,0,0,0}, b2 = {0,0,0,0}, b3 = {0,0,0,0};

#define LOADT(kk)                                               \
  {                                                             \
    const size_t o = (size_t)(kk) * 64;                         \
    a0 = *(const uint4*)(ga + o);                               \
    a1 = *(const uint4*)(ga + aK64 + o);                        \
    a2 = *(const uint4*)(ga + o + 32);                          \
    a3 = *(const uint4*)(ga + aK64 + o + 32);                   \
    b0 = *(const uint4*)(gb + o);                               \
    if (TN == 128) {                                            \
      b1 = *(const uint4*)(gb + aK64 + o);                      \
      b2 = *(const uint4*)(gb + o + 32);                        \
      b3 = *(const uint4*)(gb + aK64 + o + 32);                 \
    }                                                           \
  }
#define STORET()                                                \
  {                                                             \
    *(uint4*)&As[t * 8] = a0;                                   \
    *(uint4*)&As[t * 8 + 2048] = a1;                            \
    *(uint4*)&As[t * 8 + 4096] = a2;                            \
    *(uint4*)&As[t * 8 + 6144] = a3;                            \
    if (TN == 128) {                                            \
      *(uint4*)&Bs[t * 8] = b0;                                 \
      *(uint4*)&Bs[t * 8 + 2048] = b1;                          \
      *(uint4*)&Bs[t * 8 + 4096] = b2;                          \
      *(uint4*)&Bs[t * 8 + 6144] = b3;                          \
    } else {                                                    \
      *(uint4*)&Bs[t * 8] = b0;                                 \
    }                                                           \
  }

  const int nk = Ks / 64;
  LOADT(0);

  for (int k0 = 0; k0 < nk; ++k0) {
    __syncthreads();   // prior iteration's LDS reads complete
    STORET();          // vmcnt: loads issued ~1 full iter ago
    __syncthreads();
    if (k0 + 1 < nk) LOADT(k0 + 1);

#pragma unroll
    for (int kk = 0; kk < 2; ++kk) {
      const ushortT* arp = &As[kk * 4096 + (wr >> 4) * 512 + lane * 8];
      const ushortT* brp = (TN == 128)
          ? &Bs[kk * 4096 + (wc >> 4) * 512 + lane * 8]
          : &Bs[kk * 1024 + (wc >> 4) * 512 + lane * 8];
      short8 af[4], bf[NF];
#pragma unroll
      for (int mt = 0; mt < 4; ++mt) af[mt] = *(const short8*)(arp + mt * 512);
#pragma unroll
      for (int nt = 0; nt < NF; ++nt) bf[nt] = *(const short8*)(brp + nt * 512);
#pragma unroll
      for (int mt = 0; mt < 4; ++mt)
#pragma unroll
        for (int nt = 0; nt < NF; ++nt)
          acc[mt][nt] = __builtin_amdgcn_mfma_f32_16x16x32_bf16(af[mt], bf[nt], acc[mt][nt], 0, 0, 0);
    }
  }
#undef LOADT
#undef STORET

  // C/D layout: col = lane&15, row = quad*4 + reg
  if (MODE == EP_LOSS) {
    __shared__ float red[256];
    float lsum = 0.f;
#pragma unroll
    for (int mt = 0; mt < 4; ++mt) {
#pragma unroll
      for (int r = 0; r < 4; ++r) {
        const int row = bm + wr + mt * 16 + quad * 4 + r;
        const float w = wrow[row];
        const ushortT* xr = xa + (size_t)row * N;
        float rs = 0.f;
#pragma unroll
        for (int nt = 0; nt < NF; ++nt) {
          const int col = bn + wc + nt * 16 + lm;
          const float d = bf2f(xr[col]) - (acc[mt][nt][r] + bias[col]);
          rs = fmaf(d, d, rs);
        }
        lsum = fmaf(w, rs, lsum);
      }
    }
    __syncthreads();
    red[t] = lsum;
    __syncthreads();
    for (int st = 128; st > 0; st >>= 1) {
      if (t < st) red[t] += red[t + st];
      __syncthreads();
    }
    if (t == 0) atomicAdd(out, red[0] * (1.0f / (float)NROWS));
  } else if (MODE == EP_PART) {
#pragma unroll
    for (int mt = 0; mt < 4; ++mt)
#pragma unroll
      for (int r = 0; r < 4; ++r) {
        const int row = bm + wr + mt * 16 + quad * 4 + r;
#pragma unroll
        for (int nt = 0; nt < NF; ++nt) {
          const int col = bn + wc + nt * 16 + lm;
          P[((size_t)blockIdx.z * M + row) * N + col] = acc[mt][nt][r];
        }
      }
  } else {
#pragma unroll
    for (int mt = 0; mt < 4; ++mt)
#pragma unroll
      for (int r = 0; r < 4; ++r) {
        const int row = bm + wr + mt * 16 + quad * 4 + r;
#pragma unroll
        for (int nt = 0; nt < NF; ++nt) {
          const int col = bn + wc + nt * 16 + lm;
          float v = acc[mt][nt][r] + bias[col];
          if (MODE == EP_RELU) v = fmaxf(v, 0.f);
          C[(size_t)row * N + col] = f2bf(v);
        }
      }
  }
}

// R8 BK=32 relay GEMM -- used only for U1 (K=32, single iteration).
template <int MODE, int TN>
__global__ __launch_bounds__(256) __attribute__((amdgpu_waves_per_eu(1, 2)))
void gemm_sb(
    const ushortT* __restrict__ A, const ushortT* __restrict__ BT,
    const float* __restrict__ bias, ushortT* __restrict__ C,
    int M, int N, int K,
    const ushortT* __restrict__ xa, const float* __restrict__ wrow,
    float* __restrict__ out) {
  constexpr int NF = TN / 32;
  __shared__ __align__(16) ushortT As[4096];
  __shared__ __align__(16) ushortT Bs[TN * 32];

  const int t = threadIdx.x;
  const int wave = t >> 6;
  const int lane = t & 63;
  const int quad = lane >> 4;
  const int lm = lane & 15;
  const int bm = blockIdx.y * 128;
  const int bn = blockIdx.x * TN;
  const int wr = (wave >> 1) * 64;
  const int wc = (wave & 1) * (TN / 2);

  f32x4 acc[4][NF];
#pragma unroll
  for (int i = 0; i < 4; ++i)
#pragma unroll
    for (int j = 0; j < NF; ++j) acc[i][j] = (f32x4)0.f;

  const int a_r0 = (t >> 6) * 16 + (t & 15);
  const int a_q8 = ((t >> 4) & 3) * 8;
  const ushortT* ga0 = A + (size_t)(bm + a_r0) * K + a_q8;
  const ushortT* ga1 = ga0 + (size_t)64 * K;
  const ushortT* gb0 = BT + (size_t)(bn + a_r0) * K + a_q8;
  const ushortT* gb1 = gb0 + (size_t)64 * K;

  uint4 ra0 = *(const uint4*)ga0;
  uint4 ra1 = *(const uint4*)ga1;
  uint4 rb0 = *(const uint4*)gb0;
  uint4 rb1 = *(const uint4*)gb1;
  ga0 += 32; ga1 += 32; gb0 += 32; gb1 += 32;

  const ushortT* arp = As + (wr >> 4) * 512 + lane * 8;
  const ushortT* brp = Bs + (wc >> 4) * 512 + lane * 8;

  for (int k0 = 0; k0 < K; k0 += 32) {
    __syncthreads();
    *(uint4*)&As[t * 8] = ra0;
    *(uint4*)&As[t * 8 + 2048] = ra1;
    *(uint4*)&Bs[t * 8] = rb0;
    *(uint4*)&Bs[t * 8 + 2048] = rb1;
    __syncthreads();
    if (k0 + 32 < K) {
      ra0 = *(const uint4*)ga0;
      ra1 = *(const uint4*)ga1;
      rb0 = *(const uint4*)gb0;
      rb1 = *(const uint4*)gb1;
      ga0 += 32; ga1 += 32; gb0 += 32; gb1 += 32;
    }
    short8 af[4], bf[NF];
#pragma unroll
    for (int mt = 0; mt < 4; ++mt) af[mt] = *(const short8*)(arp + mt * 512);
#pragma unroll
    for (int nt = 0; nt < NF; ++nt) bf[nt] = *(const short8*)(brp + nt * 512);
#pragma unroll
    for (int mt = 0; mt < 4; ++mt)
#pragma unroll
      for (int nt = 0; nt < NF; ++nt)
        acc[mt][nt] = __builtin_amdgcn_mfma_f32_16x16x32_bf16(af[mt], bf[nt], acc[mt][nt], 0, 0, 0);
  }

#pragma unroll
  for (int mt = 0; mt < 4; ++mt)
#pragma unroll
    for (int r = 0; r < 4; ++r) {
      const int row = bm + wr + mt * 16 + quad * 4 + r;
#pragma unroll
      for (int nt = 0; nt < NF; ++nt) {
        const int col = bn + wc + nt * 16 + lm;
        float v = acc[mt][nt][r] + bias[col];
        if (MODE == EP_RELU) v = fmaxf(v, 0.f);
        C[(size_t)row * N + col] = f2bf(v);
      }
    }
}

// sum split-K fp32 partials + bias -> bf16. N power of 2 (Nmask = N-1).
template <int S>
__global__ __launch_bounds__(256) void reduce_lin(
    const float* __restrict__ P, const float* __restrict__ bias,
    ushortT* __restrict__ outp, int MN, int Nmask) {
  const int i4 = (blockIdx.x * 256 + threadIdx.x) * 4;
  if (i4 >= MN) return;
  float4 s = *(const float4*)(P + i4);
#pragma unroll
  for (int k = 1; k < S; ++k) {
    const float4 q = *(const float4*)(P + (size_t)k * MN + i4);
    s.x += q.x; s.y += q.y; s.z += q.z; s.w += q.w;
  }
  const float4 b = *(const float4*)(bias + (i4 & Nmask));
  ushort4 o;
  o.x = f2bf(s.x + b.x); o.y = f2bf(s.y + b.y);
  o.z = f2bf(s.z + b.z); o.w = f2bf(s.w + b.w);
  *(ushort4*)(outp + i4) = o;
}

// Frozen-mask apply on raw pre-activations U (rows x 1024 bf16):
// rows < 4096 (neighbors): out = (U[center_row] > 0) ? U : 0
// rows >= 4096 (centers):  out = relu(U)
__global__ __launch_bounds__(256) void mask_apply(
    const ushortT* __restrict__ U, ushortT* __restrict__ outp) {
  const int i4 = (blockIdx.x * 256 + threadIdx.x) * 4;
  const int r = i4 >> 10;
  const int c = i4 & 1023;
  ushort4 u = *(const ushort4*)(U + i4);
  ushort4 o;
  if (r < NROWS) {
    const ushort4 m = *(const ushort4*)(U + (((size_t)(NROWS + (r >> 5))) << 10) + c);
    o.x = ((short)m.x > 0) ? u.x : 0;
    o.y = ((short)m.y > 0) ? u.y : 0;
    o.z = ((short)m.z > 0) ? u.z : 0;
    o.w = ((short)m.w > 0) ? u.w : 0;
  } else {
    o.x = ((short)u.x > 0) ? u.x : 0;
    o.y = ((short)u.y > 0) ? u.y : 0;
    o.z = ((short)u.z > 0) ? u.z : 0;
    o.w = ((short)u.w > 0) ? u.w : 0;
  }
  *(ushort4*)(outp + i4) = o;
}

// Fused prep: x fp32 -> bf16 A_enc; per-(b,n) weights from dist^2; zero out[0].
__global__ __launch_bounds__(256) void prep_kernel(
    const float* __restrict__ x_c, const float* __restrict__ x_nn,
    ushortT* __restrict__ A_enc, float* __restrict__ wbuf, float* __restrict__ out) {
  const int i = blockIdx.x;
  const int t = threadIdx.x;
  if (i < NROWS) {
    const float* src = x_nn + (size_t)i * D_DIM;
    const float* ctr = x_c + (size_t)(i >> 5) * D_DIM;
    ushortT* dst = A_enc + (size_t)i * D_DIM;
    float s = 0.f;
    for (int d = t * 4; d < D_DIM; d += 1024) {
      const float4 v = *(const float4*)(src + d);
      const float4 c = *(const float4*)(ctr + d);
      ushort4 o;
      o.x = f2bf(v.x); o.y = f2bf(v.y); o.z = f2bf(v.z); o.w = f2bf(v.w);
      *(ushort4*)(dst + d) = o;
      const float dx = v.x - c.x, dy = v.y - c.y, dz = v.z - c.z, dw = v.w - c.w;
      s += dx * dx + dy * dy + dz * dz + dw * dw;
    }
    __shared__ float red[256];
    red[t] = s;
    __syncthreads();
    for (int st = 128; st > 0; st >>= 1) {
      if (t < st) red[t] += red[t + st];
      __syncthreads();
    }
    if (t == 0) {
      wbuf[i] = (red[0] > 1e-24f) ? 1.0f : 0.5f;
      if (i == 0) out[0] = 0.f;
    }
  } else {
    const int r = i - NROWS;
    const float* src = x_c + (size_t)r * D_DIM;
    ushortT* dst = A_enc + (size_t)i * D_DIM;
    for (int d = t * 4; d < D_DIM; d += 1024) {
      const float4 v = *(const float4*)(src + d);
      ushort4 o;
      o.x = f2bf(v.x); o.y = f2bf(v.y); o.z = f2bf(v.z); o.w = f2bf(v.w);
      *(ushort4*)(dst + d) = o;
    }
  }
}

// Batched transpose+cast of all six weights: W (KxN f32) -> WT (NxK bf16).
__global__ __launch_bounds__(256) void trans_all(
    const float* __restrict__ We1, const float* __restrict__ We2,
    const float* __restrict__ We3, const float* __restrict__ Wd1,
    const float* __restrict__ Wd2, const float* __restrict__ Wd3,
    ushortT* __restrict__ We1T, ushortT* __restrict__ We2T,
    ushortT* __restrict__ We3T, ushortT* __restrict__ Wd1T,
    ushortT* __restrict__ Wd2T, ushortT* __restrict__ Wd3T) {
  const int b = blockIdx.x;
  const float* W; ushortT* WT; int K, N, loc;
  if (b < 3072)      { W = We1; WT = We1T; K = 3072; N = 1024; loc = b; }
  else if (b < 4096) { W = We2; WT = We2T; K = 1024; N = 1024; loc = b - 3072; }
  else if (b < 4128) { W = We3; WT = We3T; K = 1024; N = 32;   loc = b - 4096; }
  else if (b < 4160) { W = Wd1; WT = Wd1T; K = 32;   N = 1024; loc = b - 4128; }
  else if (b < 5184) { W = Wd2; WT = Wd2T; K = 1024; N = 1024; loc = b - 4160; }
  else               { W = Wd3; WT = Wd3T; K = 1024; N = 3072; loc = b - 5184; }
  const int ntiles = N >> 5;
  const int n0 = (loc % ntiles) * 32;
  const int k0 = (loc / ntiles) * 32;
  __shared__ float tile[32][33];
  const int tx = threadIdx.x & 31;
  const int ty = threadIdx.x >> 5;
  for (int i = ty; i < 32; i += 8)
    tile[i][tx] = W[(size_t)(k0 + i) * N + n0 + tx];
  __syncthreads();
  for (int i = ty; i < 32; i += 8)
    WT[(size_t)(n0 + i) * K + k0 + tx] = f2bf(tile[tx][i]);
}

extern "C" void kernel_launch(void* const* d_in, const int* in_sizes, int n_in,
                              void* d_out, int out_size, void* d_ws, size_t ws_size,
                              hipStream_t stream) {
  const float* x_c = (const float*)d_in[0];
  const float* x_nn = (const float*)d_in[1];
  const float* We1 = (const float*)d_in[2];
  const float* be1 = (const float*)d_in[3];
  const float* We2 = (const float*)d_in[4];
  const float* be2 = (const float*)d_in[5];
  const float* We3 = (const float*)d_in[6];
  const float* be3 = (const float*)d_in[7];
  const float* Wd1 = (const float*)d_in[8];
  const float* bd1 = (const float*)d_in[9];
  const float* Wd2 = (const float*)d_in[10];
  const float* bd2 = (const float*)d_in[11];
  const float* Wd3 = (const float*)d_in[12];
  const float* bd3 = (const float*)d_in[13];
  float* out = (float*)d_out;

  char* p = (char*)d_ws;
  auto alloc = [&](size_t bytes) {
    char* r = p;
    p += (bytes + 255) & ~(size_t)255;
    return r;
  };
  ushortT* We1T = (ushortT*)alloc((size_t)H_DIM * D_DIM * 2);
  ushortT* We2T = (ushortT*)alloc((size_t)H_DIM * H_DIM * 2);
  ushortT* We3T = (ushortT*)alloc((size_t)Z_DIM * H_DIM * 2);
  ushortT* Wd1T = (ushortT*)alloc((size_t)H_DIM * Z_DIM * 2);
  ushortT* Wd2T = (ushortT*)alloc((size_t)H_DIM * H_DIM * 2);
  ushortT* Wd3T = (ushortT*)alloc((size_t)D_DIM * H_DIM * 2);
  ushortT* A_enc = (ushortT*)alloc((size_t)MENC * D_DIM * 2);
  ushortT* bufX = (ushortT*)alloc((size_t)MENC * H_DIM * 2);  // h1 / U1 / U2
  ushortT* bufY = (ushortT*)alloc((size_t)MENC * H_DIM * 2);  // h2 / A2 / t2
  ushortT* z = (ushortT*)alloc((size_t)MENC * Z_DIM * 2);
  float* Pz = (float*)alloc((size_t)8 * MENC * Z_DIM * 4);
  float* wbuf = (float*)alloc((size_t)NROWS * 4);

  const dim3 blk(256);
  const float* nofp = nullptr;
  const ushortT* nobf = nullptr;

  // x -> bf16, per-neighbor weights, zero loss accumulator; weights -> bf16^T
  prep_kernel<<<dim3(MENC), blk, 0, stream>>>(x_c, x_nn, A_enc, wbuf, out);
  trans_all<<<dim3(8256), blk, 0, stream>>>(We1, We2, We3, Wd1, Wd2, Wd3,
                                            We1T, We2T, We3T, Wd1T, Wd2T, Wd3T);

  // encoder on [x_nn; x_c] (4224 rows), BK=64
  gemm64<EP_RELU, 128><<<dim3(8, 33, 1), blk, 0, stream>>>(
      A_enc, We1T, be1, bufX, nullptr, MENC, H_DIM, D_DIM, D_DIM, nobf, nofp, nullptr);
  gemm64<EP_RELU, 128><<<dim3(8, 33, 1), blk, 0, stream>>>(
      bufX, We2T, be2, bufY, nullptr, MENC, H_DIM, H_DIM, H_DIM, nobf, nofp, nullptr);
  // z = h2 @ We3 + be3 (N=32): split-K S=8 -> 264 blocks, 2 iters each
  gemm64<EP_PART, 32><<<dim3(1, 33, 8), blk, 0, stream>>>(
      bufY, We3T, nofp, nullptr, Pz, MENC, Z_DIM, H_DIM, H_DIM / 8, nobf, nofp, nullptr);
  reduce_lin<8><<<dim3((MENC * Z_DIM) / 1024), blk, 0, stream>>>(
      Pz, be3, z, MENC * Z_DIM, Z_DIM - 1);

  // linearized decoder with frozen center masks (exact for ReLU MLP):
  // U1 = [z_nn; z_c] @ Wd1 + bd1 (K=32, single BK32 iteration)
  gemm_sb<EP_BIAS, 128><<<dim3(8, 33), blk, 0, stream>>>(
      z, Wd1T, bd1, bufX, MENC, H_DIM, Z_DIM, nobf, nofp, nullptr);
  // A2 = mask1 .* U1 (neighbors), relu(U1) (centers)
  mask_apply<<<dim3((MENC * H_DIM) / 1024), blk, 0, stream>>>(bufX, bufY);
  // U2 = A2 @ Wd2 + bd2 (raw, all rows)
  gemm64<EP_BIAS, 128><<<dim3(8, 33, 1), blk, 0, stream>>>(
      bufY, Wd2T, bd2, bufX, nullptr, MENC, H_DIM, H_DIM, H_DIM, nobf, nofp, nullptr);
  // t2 = mask2 .* U2 (neighbor rows only)
  mask_apply<<<dim3((NROWS * H_DIM) / 1024), blk, 0, stream>>>(bufX, bufY);
  // loss GEMM: pred = t2 @ Wd3 + bd3, fused weighted-SSE vs bf16 x_nn
  gemm64<EP_LOSS, 128><<<dim3(24, 32, 1), blk, 0, stream>>>(
      bufY, Wd3T, bd3, nullptr, nullptr, NROWS, D_DIM, H_DIM, H_DIM, A_enc, wbuf, out);
}